// Round 1
// baseline (4385.953 us; speedup 1.0000x reference)
//
#include <hip/hip_runtime.h>

#define HW 128
#define COUT 512
#define NB 4097          // buckets for score-bits radix (d>>11, d in [0, 0x800000])
#define NSEL 300

// ---------------- ws layout (bytes) ----------------
#define WS_X1     ((size_t)0)          // 16384*512*4 = 33554432
#define WS_X2     ((size_t)33554432)   // 33554432
#define WS_BOXES  ((size_t)67108864)   // 147456*16 = 2359296
#define WS_KEYS   ((size_t)69468160)   // 147456*8  = 1179648
#define WS_SKEYS  ((size_t)70647808)   // 1179648
#define WS_HIST   ((size_t)71827456)   // 4097*4 -> pad 16640
#define WS_CUR    ((size_t)71844096)   // pad 16640
#define WS_CNT    ((size_t)71860736)   // pad 256
#define WS_BASE   ((size_t)71860992)   // 4098*4 = 16392
// total ~71.88 MB

// ---------------- conv 3x3 as implicit GEMM ----------------
// out[h][w][oc] = sum_{ky,kx,ic} act(in[h+ky-1][w+kx-1][ic]) * wgt[(ky*3+kx)*CIN+ic][oc] + bias[oc]
// Tile: BM=64 (one h row-segment), BN=64, BK=32. 256 threads, 4x4 acc each.
template<int CIN, bool RELU_IN, bool RELU_OUT>
__global__ __launch_bounds__(256) void conv3x3_kernel(
    const float* __restrict__ in,    // [128][128][CIN]
    const float* __restrict__ wgt,   // [9*CIN][512]
    const float* __restrict__ bias,  // [512]
    float* __restrict__ out)         // [128][128][512]
{
    __shared__ float As[32][68];   // [k][pixel], padded
    __shared__ float Bs[32][64];   // [k][n]

    int bx    = blockIdx.x;
    int mtile = bx & 255;          // 0..255
    int ntile = bx >> 8;           // 0..7
    int h  = mtile >> 1;
    int w0 = (mtile & 1) << 6;
    int n0 = ntile << 6;

    int tid = threadIdx.x;
    int ty = tid >> 4;             // 0..15
    int tx = tid & 15;             // 0..15

    float acc[4][4] = {{0.f}};

    const int KTOT = 9 * CIN;
    for (int k0 = 0; k0 < KTOT; k0 += 32) {
        int tap = k0 / CIN;        // CIN is power of two -> shifts
        int icb = k0 % CIN;
        int dy = tap / 3 - 1;
        int dx = tap % 3 - 1;
        int row = h + dy;
        bool rowok = ((unsigned)row < HW);

        // ---- stage A: 64 pixels x 32 channels ----
        {
            int pix = tid >> 3;            // 0..31
            int cs  = (tid & 7) << 2;      // 0,4,...,28
            #pragma unroll
            for (int p = 0; p < 2; ++p) {
                int px = pix + p * 32;     // 0..63
                int wcol = w0 + px + dx;
                float4 v = make_float4(0.f, 0.f, 0.f, 0.f);
                if (rowok && (unsigned)wcol < HW) {
                    v = *(const float4*)&in[((size_t)row * HW + wcol) * CIN + icb + cs];
                    if (RELU_IN) {
                        v.x = fmaxf(v.x, 0.f); v.y = fmaxf(v.y, 0.f);
                        v.z = fmaxf(v.z, 0.f); v.w = fmaxf(v.w, 0.f);
                    }
                }
                As[cs + 0][px] = v.x;
                As[cs + 1][px] = v.y;
                As[cs + 2][px] = v.z;
                As[cs + 3][px] = v.w;
            }
        }
        // ---- stage B: 32 k-rows x 64 n ----
        {
            int kr = tid >> 4;             // 0..15
            int nc = (tid & 15) << 2;
            #pragma unroll
            for (int p = 0; p < 2; ++p) {
                int k = kr + p * 16;
                float4 v = *(const float4*)&wgt[(size_t)(k0 + k) * COUT + n0 + nc];
                *(float4*)&Bs[k][nc] = v;
            }
        }
        __syncthreads();

        #pragma unroll
        for (int kk = 0; kk < 32; ++kk) {
            float4 a = *(const float4*)&As[kk][ty << 2];
            float4 b = *(const float4*)&Bs[kk][tx << 2];
            float av[4] = {a.x, a.y, a.z, a.w};
            float bv[4] = {b.x, b.y, b.z, b.w};
            #pragma unroll
            for (int i = 0; i < 4; ++i)
                #pragma unroll
                for (int j = 0; j < 4; ++j)
                    acc[i][j] = fmaf(av[i], bv[j], acc[i][j]);
        }
        __syncthreads();
    }

    // ---- epilogue ----
    float4 bi = *(const float4*)&bias[n0 + (tx << 2)];
    float bv2[4] = {bi.x, bi.y, bi.z, bi.w};
    #pragma unroll
    for (int i = 0; i < 4; ++i) {
        int m = (ty << 2) + i;
        float4 o;
        o.x = acc[i][0] + bv2[0];
        o.y = acc[i][1] + bv2[1];
        o.z = acc[i][2] + bv2[2];
        o.w = acc[i][3] + bv2[3];
        if (RELU_OUT) {
            o.x = fmaxf(o.x, 0.f); o.y = fmaxf(o.y, 0.f);
            o.z = fmaxf(o.z, 0.f); o.w = fmaxf(o.w, 0.f);
        }
        *(float4*)&out[((size_t)(h * HW) + w0 + m) * COUT + n0 + (tx << 2)] = o;
    }
}

// ---------------- heads (1x1 convs) + sigmoid + decode + candidate filter ----------------
// One wave per pixel; lanes 0..44 each compute one of the 45 outputs (9 score + 36 box).
__global__ __launch_bounds__(256) void heads_decode_kernel(
    const float* __restrict__ x,     // [16384][512]
    const float* __restrict__ w_s,   // [512][9]
    const float* __restrict__ b_s,   // [9]
    const float* __restrict__ w_b,   // [512][36]
    const float* __restrict__ b_b,   // [36]
    float4* __restrict__ boxes,      // [147456]
    unsigned long long* __restrict__ keys,  // compact candidate keys
    int* __restrict__ cnt,           // [1]
    int* __restrict__ hist)          // [NB]
{
    __shared__ float xs[4][512];
    __shared__ float outs[4][45];

    int wave = threadIdx.x >> 6;
    int lane = threadIdx.x & 63;
    int pix  = blockIdx.x * 4 + wave;

    const float4* xp = (const float4*)&x[(size_t)pix * COUT];
    *(float4*)&xs[wave][lane * 4]       = xp[lane];
    *(float4*)&xs[wave][256 + lane * 4] = xp[64 + lane];
    __syncthreads();

    if (lane < 45) {
        const float* wp;
        int stride;
        float acc;
        if (lane < 9) { wp = w_s + lane;       stride = 9;  acc = b_s[lane]; }
        else          { wp = w_b + (lane - 9); stride = 36; acc = b_b[lane - 9]; }
        const float* xrow = xs[wave];
        for (int k = 0; k < 512; k += 4) {
            acc = fmaf(xrow[k + 0], wp[(k + 0) * stride], acc);
            acc = fmaf(xrow[k + 1], wp[(k + 1) * stride], acc);
            acc = fmaf(xrow[k + 2], wp[(k + 2) * stride], acc);
            acc = fmaf(xrow[k + 3], wp[(k + 3) * stride], acc);
        }
        outs[wave][lane] = acc;
    }
    __syncthreads();

    if (lane < 9) {
        int h = pix >> 7, w = pix & 127;
        int a = lane;
        float z   = outs[wave][a];
        float dyv = outs[wave][9 + 4 * a + 0];
        float dxv = outs[wave][9 + 4 * a + 1];
        float dhv = outs[wave][9 + 4 * a + 2];
        float dwv = outs[wave][9 + 4 * a + 3];

        float scale = (a < 3) ? 128.f : ((a < 6) ? 256.f : 512.f);
        int r = a - (a / 3) * 3;
        float ratio = (r == 0) ? 0.5f : ((r == 1) ? 1.f : 2.f);
        float sr = sqrtf(ratio);
        float ah = scale * sr;
        float aw = scale / sr;
        float acy = ((float)h + 0.5f) * 16.f;
        float acx = ((float)w + 0.5f) * 16.f;

        float cy = fmaf(dyv, ah, acy);
        float cx = fmaf(dxv, aw, acx);
        float hh = ah * expf(dhv);
        float ww = aw * expf(dwv);
        float y1 = fminf(fmaxf(cy - 0.5f * hh, 0.f), 2048.f);
        float x1 = fminf(fmaxf(cx - 0.5f * ww, 0.f), 2048.f);
        float y2 = fminf(fmaxf(cy + 0.5f * hh, 0.f), 2048.f);
        float x2 = fminf(fmaxf(cx + 0.5f * ww, 0.f), 2048.f);

        int gi = pix * 9 + a;
        boxes[gi] = make_float4(y1, x1, y2, x2);

        float s = 1.f / (1.f + expf(-z));
        if (s >= 0.5f) {
            unsigned u = __float_as_uint(s);
            unsigned d = 0x3F800000u - u;  // monotone-descending score key, d in [0, 0x800000]
            unsigned long long key = ((unsigned long long)d << 18) | (unsigned)gi;
            int p = atomicAdd(cnt, 1);
            keys[p] = key;
            atomicAdd(&hist[d >> 11], 1);
        }
    }
}

// ---------------- exclusive scan over NB buckets ----------------
__global__ __launch_bounds__(256) void scan_kernel(
    const int* __restrict__ hist, int* __restrict__ base)
{
    __shared__ int buf[256];
    __shared__ int carry;
    int tid = threadIdx.x;
    if (tid == 0) carry = 0;
    __syncthreads();
    for (int c = 0; c < NB; c += 256) {
        int idx = c + tid;
        int v = (idx < NB) ? hist[idx] : 0;
        buf[tid] = v;
        __syncthreads();
        for (int s = 1; s < 256; s <<= 1) {
            int t = (tid >= s) ? buf[tid - s] : 0;
            __syncthreads();
            buf[tid] += t;
            __syncthreads();
        }
        if (idx < NB) base[idx] = carry + buf[tid] - v;
        __syncthreads();
        if (tid == 0) carry += buf[255];
        __syncthreads();
    }
    if (tid == 0) base[NB] = carry;
}

// ---------------- scatter into bucket-sorted order ----------------
__global__ __launch_bounds__(256) void scatter_kernel(
    const unsigned long long* __restrict__ keys,
    const int* __restrict__ cnt,
    const int* __restrict__ base,
    int* __restrict__ cur,
    unsigned long long* __restrict__ skeys)
{
    int i = blockIdx.x * 256 + threadIdx.x;
    if (i < *cnt) {
        unsigned long long k = keys[i];
        int b = (int)(k >> 29);   // (d>>11)
        int p = base[b] + atomicAdd(&cur[b], 1);
        skeys[p] = k;
    }
}

// ---------------- greedy NMS over bucket-sorted candidates ----------------
__global__ __launch_bounds__(256) void nms_kernel(
    unsigned long long* __restrict__ skeys,
    const int* __restrict__ base,
    const float4* __restrict__ boxes,
    float* __restrict__ out)
{
    __shared__ float4 sbox[NSEL];
    __shared__ float  sarea[NSEL];
    __shared__ unsigned long long buf[4096];
    __shared__ unsigned long long rmin[256];
    __shared__ int ridx[256];
    __shared__ int selCount;
    __shared__ int flag;

    int tid = threadIdx.x;
    for (int i = tid; i < 1800; i += 256) out[i] = 0.f;
    if (tid == 0) selCount = 0;
    __syncthreads();

    for (int b = 0; b < NB; ++b) {
        if (selCount >= NSEL) break;
        int s0 = base[b];
        int n  = base[b + 1] - s0;
        if (n <= 0) continue;

        bool use_lds = (n <= 4096);
        unsigned long long* bp = use_lds ? buf : (skeys + s0);
        if (use_lds) {
            for (int i = tid; i < n; i += 256) buf[i] = skeys[s0 + i];
        }
        __syncthreads();

        while (true) {
            // block-wide min extraction (exact total order: score desc, index asc)
            unsigned long long mv = ~0ull;
            int mi = -1;
            for (int i = tid; i < n; i += 256) {
                unsigned long long v = bp[i];
                if (v < mv) { mv = v; mi = i; }
            }
            rmin[tid] = mv; ridx[tid] = mi;
            __syncthreads();
            for (int s = 128; s > 0; s >>= 1) {
                if (tid < s) {
                    if (rmin[tid + s] < rmin[tid]) {
                        rmin[tid] = rmin[tid + s];
                        ridx[tid] = ridx[tid + s];
                    }
                }
                __syncthreads();
            }
            unsigned long long key = rmin[0];
            if (key == ~0ull) break;   // bucket exhausted

            int sc = selCount;
            if (tid == 0) { bp[ridx[0]] = ~0ull; flag = 0; }
            __syncthreads();

            unsigned gi = (unsigned)(key & 0x3FFFFull);
            float4 cb = boxes[gi];
            float ca = (cb.z - cb.x) * (cb.w - cb.y);
            for (int t = tid; t < sc; t += 256) {
                float4 s4 = sbox[t];
                float iy = fmaxf(0.f, fminf(s4.z, cb.z) - fmaxf(s4.x, cb.x));
                float ix = fmaxf(0.f, fminf(s4.w, cb.w) - fmaxf(s4.y, cb.y));
                float inter = iy * ix;
                float iou = inter / (sarea[t] + ca - inter + 1e-9f);
                if (iou > 0.7f) flag = 1;
            }
            __syncthreads();

            if (flag == 0) {
                if (tid == 0) {
                    int c = selCount;
                    sbox[c] = cb;
                    sarea[c] = ca;
                    out[c * 4 + 0] = cb.x;
                    out[c * 4 + 1] = cb.y;
                    out[c * 4 + 2] = cb.z;
                    out[c * 4 + 3] = cb.w;
                    out[1200 + c] = __uint_as_float(0x3F800000u - (unsigned)(key >> 18));
                    out[1500 + c] = 1.f;
                    selCount = c + 1;
                }
                __syncthreads();
                if (selCount >= NSEL) break;
            }
        }
        __syncthreads();
    }
}

extern "C" void kernel_launch(void* const* d_in, const int* in_sizes, int n_in,
                              void* d_out, int out_size, void* d_ws, size_t ws_size,
                              hipStream_t stream) {
    const float* feat = (const float*)d_in[0];
    const float* w1   = (const float*)d_in[1];
    const float* b1   = (const float*)d_in[2];
    const float* w2   = (const float*)d_in[3];
    const float* b2   = (const float*)d_in[4];
    const float* w_s  = (const float*)d_in[5];
    const float* b_s  = (const float*)d_in[6];
    const float* w_b  = (const float*)d_in[7];
    const float* b_b  = (const float*)d_in[8];
    float* out = (float*)d_out;

    char* ws = (char*)d_ws;
    float* x1 = (float*)(ws + WS_X1);
    float* x2 = (float*)(ws + WS_X2);
    float4* boxes = (float4*)(ws + WS_BOXES);
    unsigned long long* keys  = (unsigned long long*)(ws + WS_KEYS);
    unsigned long long* skeys = (unsigned long long*)(ws + WS_SKEYS);
    int* hist = (int*)(ws + WS_HIST);
    int* cur  = (int*)(ws + WS_CUR);
    int* cnt  = (int*)(ws + WS_CNT);
    int* base = (int*)(ws + WS_BASE);

    // zero hist + cur + cnt (contiguous region)
    hipMemsetAsync(ws + WS_HIST, 0, (WS_CNT - WS_HIST) + 256, stream);

    conv3x3_kernel<1024, true,  true ><<<2048, 256, 0, stream>>>(feat, w1, b1, x1);
    conv3x3_kernel< 512, false, false><<<2048, 256, 0, stream>>>(x1,   w2, b2, x2);
    heads_decode_kernel<<<4096, 256, 0, stream>>>(x2, w_s, b_s, w_b, b_b, boxes, keys, cnt, hist);
    scan_kernel<<<1, 256, 0, stream>>>(hist, base);
    scatter_kernel<<<576, 256, 0, stream>>>(keys, cnt, base, cur, skeys);
    nms_kernel<<<1, 256, 0, stream>>>(skeys, base, boxes, out);
}

// Round 2
// 1667.334 us; speedup vs baseline: 2.6305x; 2.6305x over previous
//
#include <hip/hip_runtime.h>

#define HW 128
#define COUTC 512
#define NB 4097
#define NSEL 300

typedef _Float16 half8 __attribute__((ext_vector_type(8)));
typedef _Float16 half4v __attribute__((ext_vector_type(4)));
typedef float floatx4 __attribute__((ext_vector_type(4)));

// ================= new ws layout (bytes) =================
#define NWS_A1H   ((size_t)0)            // 130*130*1024*2 = 34,611,200
#define NWS_A1L   ((size_t)34611200)
#define NWS_W1H   ((size_t)69222400)     // 512*9216*2 = 9,437,184
#define NWS_W1L   ((size_t)78659584)
#define NWS_A2H   ((size_t)88096768)     // 130*130*512*2 = 17,305,600
#define NWS_A2L   ((size_t)105402368)
#define NWS_W2H   ((size_t)122707968)    // 512*4608*2 = 4,718,592
#define NWS_W2L   ((size_t)127426560)
#define NWS_X2    ((size_t)132145152)    // 16384*512*4 = 33,554,432
#define NWS_BOXES ((size_t)165699584)    // 147456*16
#define NWS_KEYS  ((size_t)168058880)    // 147456*8
#define NWS_SKEYS ((size_t)169238528)
#define NWS_HIST  ((size_t)170418176)    // 4097*4 pad 16640
#define NWS_CUR   ((size_t)170434816)
#define NWS_CNT   ((size_t)170451456)    // pad 256
#define NWS_BASE  ((size_t)170451712)    // 4098*4
#define NWS_TOTAL ((size_t)170468352)

// ================= old (fallback) ws layout =================
#define WS_X1     ((size_t)0)
#define WS_X2     ((size_t)33554432)
#define WS_BOXES  ((size_t)67108864)
#define WS_KEYS   ((size_t)69468160)
#define WS_SKEYS  ((size_t)70647808)
#define WS_HIST   ((size_t)71827456)
#define WS_CUR    ((size_t)71844096)
#define WS_CNT    ((size_t)71860736)
#define WS_BASE   ((size_t)71860992)

__device__ __forceinline__ void glds16(const void* g, void* l) {
    __builtin_amdgcn_global_load_lds(
        (const __attribute__((address_space(1))) void*)g,
        (__attribute__((address_space(3))) void*)l, 16, 0, 0);
}

// ---------------- feature convert: relu + fp16 hi/lo split into padded planes ----------------
__global__ __launch_bounds__(256) void convert_feat_kernel(
    const float* __restrict__ feat, _Float16* __restrict__ ah, _Float16* __restrict__ al)
{
    int p  = blockIdx.x;            // 0..16899 padded pixel
    int pr = p / 130, pc = p % 130;
    int c  = threadIdx.x * 4;
    half4v vh = (half4v)(_Float16)0.f, vl = (half4v)(_Float16)0.f;
    if (pr != 0 && pr != 129 && pc != 0 && pc != 129) {
        float4 v = *(const float4*)&feat[(size_t)(((pr - 1) * HW) + (pc - 1)) * 1024 + c];
        float f[4] = {v.x, v.y, v.z, v.w};
        #pragma unroll
        for (int i = 0; i < 4; ++i) {
            float x = fmaxf(f[i], 0.f);
            _Float16 hi = (_Float16)x;
            vh[i] = hi;
            vl[i] = (_Float16)(x - (float)hi);
        }
    }
    *(half4v*)&ah[(size_t)p * 1024 + c] = vh;
    *(half4v*)&al[(size_t)p * 1024 + c] = vl;
}

// ---------------- weight convert: transpose [K][512] -> [512][K], scale x64, split hi/lo ----------------
template<int K>
__global__ __launch_bounds__(256) void convert_w_kernel(
    const float* __restrict__ w, _Float16* __restrict__ wh, _Float16* __restrict__ wl)
{
    __shared__ float t[32][33];
    int k0 = blockIdx.x * 32, oc0 = blockIdx.y * 32;
    int tx = threadIdx.x & 31, ty = threadIdx.x >> 5;   // ty 0..7
    #pragma unroll
    for (int r = 0; r < 32; r += 8)
        t[ty + r][tx] = w[(size_t)(k0 + ty + r) * COUTC + oc0 + tx] * 64.f;
    __syncthreads();
    #pragma unroll
    for (int r = 0; r < 32; r += 8) {
        int oc = oc0 + ty + r, k = k0 + tx;
        float v = t[tx][ty + r];
        _Float16 hi = (_Float16)v;
        wh[(size_t)oc * K + k] = hi;
        wl[(size_t)oc * K + k] = (_Float16)(v - (float)hi);
    }
}

// ---------------- zero the pad ring of a 130x130x512 plane pair ----------------
__global__ __launch_bounds__(256) void zero_pads_kernel(_Float16* ah, _Float16* al)
{
    int i = blockIdx.x;  // 0..515
    int pr, pc;
    if (i < 130)      { pr = 0;        pc = i; }
    else if (i < 260) { pr = 129;      pc = i - 130; }
    else if (i < 388) { pr = i - 259;  pc = 0; }     // rows 1..128
    else              { pr = i - 387;  pc = 129; }
    int p = pr * 130 + pc;
    int c = threadIdx.x * 2;
    *(unsigned*)&ah[(size_t)p * 512 + c] = 0u;
    *(unsigned*)&al[(size_t)p * 512 + c] = 0u;
}

// ---------------- conv 3x3 via fp16-split MFMA implicit GEMM ----------------
// Block tile: M=128 (image row h), N=128. 4 waves, each 64x64 (4x4 mfma_f32_16x16x32_f16).
// K-chunks of 32 over 9 taps x CIN. 3 products: hi*hi + hi*lo + lo*hi (w pre-scaled x64).
template<int CIN, bool SPLIT_OUT>
__global__ __launch_bounds__(256) void conv_mfma_kernel(
    const _Float16* __restrict__ ah, const _Float16* __restrict__ al,  // padded [130*130][CIN]
    const _Float16* __restrict__ wh, const _Float16* __restrict__ wl,  // [512][9*CIN]
    const float* __restrict__ bias,
    _Float16* __restrict__ oh, _Float16* __restrict__ ol,  // SPLIT_OUT: padded [130*130][512]
    float* __restrict__ of)                                 // !SPLIT_OUT: [16384][512]
{
    constexpr int K9 = 9 * CIN;
    __shared__ __align__(16) _Float16 lds[16384];  // AHI 0, ALO 4096, BHI 8192, BLO 12288 (halves)

    int bx = blockIdx.x;
    int h  = bx & 127;
    int n0 = (bx >> 7) << 7;

    int tid  = threadIdx.x;
    int wave = tid >> 6;
    int lane = tid & 63;

    // staging decomposition
    int sp = lane >> 2;            // 0..15
    int kq = (lane & 3) << 3;      // halves: 0,8,16,24

    int aoff0 = (32 * wave + sp) * CIN + kq;       // pixel-row part (w index)
    int aoff1 = aoff0 + 16 * CIN;
    int boff0 = (n0 + 32 * wave + sp) * K9 + kq;   // oc-row part
    int boff1 = boff0 + 16 * K9;

    _Float16* dA0 = lds +        1024 * wave;
    _Float16* dA1 = dA0 + 512;
    _Float16* dL0 = lds + 4096 + 1024 * wave;
    _Float16* dL1 = dL0 + 512;
    _Float16* dB0 = lds + 8192 + 1024 * wave;
    _Float16* dB1 = dB0 + 512;
    _Float16* dC0 = lds + 12288 + 1024 * wave;
    _Float16* dC1 = dC0 + 512;

    // compute decomposition
    int fr = lane & 15;
    int fq = lane >> 4;
    int wm = wave & 1, wn = wave >> 1;
    const _Float16* rAh = lds +         (64 * wm + fr) * 32 + fq * 8;
    const _Float16* rAl = rAh + 4096;
    const _Float16* rBh = lds + 8192 + (64 * wn + fr) * 32 + fq * 8;
    const _Float16* rBl = rBh + 4096;

    floatx4 acc[4][4];
    #pragma unroll
    for (int i = 0; i < 4; ++i)
        #pragma unroll
        for (int j = 0; j < 4; ++j)
            acc[i][j] = (floatx4){0.f, 0.f, 0.f, 0.f};

    #pragma unroll
    for (int tap = 0; tap < 9; ++tap) {
        int dy = tap / 3 - 1, dx = tap % 3 - 1;
        const _Float16* gAh = ah + (size_t)((h + dy + 1) * 130 + (dx + 1)) * CIN;
        const _Float16* gAl = al + (size_t)((h + dy + 1) * 130 + (dx + 1)) * CIN;
        const _Float16* gBh = wh + (size_t)tap * CIN;
        const _Float16* gBl = wl + (size_t)tap * CIN;

        for (int kc = 0; kc < CIN; kc += 32) {
            glds16(gAh + aoff0 + kc, dA0);
            glds16(gAh + aoff1 + kc, dA1);
            glds16(gAl + aoff0 + kc, dL0);
            glds16(gAl + aoff1 + kc, dL1);
            glds16(gBh + boff0 + kc, dB0);
            glds16(gBh + boff1 + kc, dB1);
            glds16(gBl + boff0 + kc, dC0);
            glds16(gBl + boff1 + kc, dC1);
            __syncthreads();

            half8 fah[4], fal[4], fbh[4], fbl[4];
            #pragma unroll
            for (int i = 0; i < 4; ++i) {
                fah[i] = *(const half8*)(rAh + i * 512);
                fal[i] = *(const half8*)(rAl + i * 512);
                fbh[i] = *(const half8*)(rBh + i * 512);
                fbl[i] = *(const half8*)(rBl + i * 512);
            }
            #pragma unroll
            for (int i = 0; i < 4; ++i)
                #pragma unroll
                for (int j = 0; j < 4; ++j)
                    acc[i][j] = __builtin_amdgcn_mfma_f32_16x16x32_f16(fah[i], fbh[j], acc[i][j], 0, 0, 0);
            #pragma unroll
            for (int i = 0; i < 4; ++i)
                #pragma unroll
                for (int j = 0; j < 4; ++j)
                    acc[i][j] = __builtin_amdgcn_mfma_f32_16x16x32_f16(fah[i], fbl[j], acc[i][j], 0, 0, 0);
            #pragma unroll
            for (int i = 0; i < 4; ++i)
                #pragma unroll
                for (int j = 0; j < 4; ++j)
                    acc[i][j] = __builtin_amdgcn_mfma_f32_16x16x32_f16(fal[i], fbh[j], acc[i][j], 0, 0, 0);
            __syncthreads();
        }
    }

    // epilogue: out = acc/64 + bias
    const float scale = 1.f / 64.f;
    int em = 64 * wm + fq * 4;
    int en = 64 * wn + fr;
    #pragma unroll
    for (int j = 0; j < 4; ++j) {
        int oc = n0 + en + 16 * j;
        float b = bias[oc];
        #pragma unroll
        for (int i = 0; i < 4; ++i) {
            #pragma unroll
            for (int r = 0; r < 4; ++r) {
                int w = em + 16 * i + r;
                float v = fmaf(acc[i][j][r], scale, b);
                if (SPLIT_OUT) {
                    v = fmaxf(v, 0.f);
                    _Float16 hi = (_Float16)v;
                    size_t o = ((size_t)(h + 1) * 130 + (w + 1)) * COUTC + oc;
                    oh[o] = hi;
                    ol[o] = (_Float16)(v - (float)hi);
                } else {
                    of[((size_t)h * HW + w) * COUTC + oc] = v;
                }
            }
        }
    }
}

// ---------------- OLD fp32 conv (fallback when ws is small) ----------------
template<int CIN, bool RELU_IN, bool RELU_OUT>
__global__ __launch_bounds__(256) void conv3x3_kernel(
    const float* __restrict__ in, const float* __restrict__ wgt,
    const float* __restrict__ bias, float* __restrict__ out)
{
    __shared__ float As[32][68];
    __shared__ float Bs[32][64];
    int bx = blockIdx.x;
    int mtile = bx & 255, ntile = bx >> 8;
    int h = mtile >> 1, w0 = (mtile & 1) << 6, n0 = ntile << 6;
    int tid = threadIdx.x, ty = tid >> 4, tx = tid & 15;
    float acc[4][4] = {{0.f}};
    const int KTOT = 9 * CIN;
    for (int k0 = 0; k0 < KTOT; k0 += 32) {
        int tap = k0 / CIN, icb = k0 % CIN;
        int dy = tap / 3 - 1, dx = tap % 3 - 1;
        int row = h + dy;
        bool rowok = ((unsigned)row < HW);
        {
            int pix = tid >> 3, cs = (tid & 7) << 2;
            #pragma unroll
            for (int p = 0; p < 2; ++p) {
                int px = pix + p * 32;
                int wcol = w0 + px + dx;
                float4 v = make_float4(0.f, 0.f, 0.f, 0.f);
                if (rowok && (unsigned)wcol < HW) {
                    v = *(const float4*)&in[((size_t)row * HW + wcol) * CIN + icb + cs];
                    if (RELU_IN) {
                        v.x = fmaxf(v.x, 0.f); v.y = fmaxf(v.y, 0.f);
                        v.z = fmaxf(v.z, 0.f); v.w = fmaxf(v.w, 0.f);
                    }
                }
                As[cs + 0][px] = v.x; As[cs + 1][px] = v.y;
                As[cs + 2][px] = v.z; As[cs + 3][px] = v.w;
            }
        }
        {
            int kr = tid >> 4, nc = (tid & 15) << 2;
            #pragma unroll
            for (int p = 0; p < 2; ++p) {
                int k = kr + p * 16;
                *(float4*)&Bs[k][nc] = *(const float4*)&wgt[(size_t)(k0 + k) * COUTC + n0 + nc];
            }
        }
        __syncthreads();
        #pragma unroll
        for (int kk = 0; kk < 32; ++kk) {
            float4 a = *(const float4*)&As[kk][ty << 2];
            float4 b = *(const float4*)&Bs[kk][tx << 2];
            float av[4] = {a.x, a.y, a.z, a.w};
            float bv[4] = {b.x, b.y, b.z, b.w};
            #pragma unroll
            for (int i = 0; i < 4; ++i)
                #pragma unroll
                for (int j = 0; j < 4; ++j)
                    acc[i][j] = fmaf(av[i], bv[j], acc[i][j]);
        }
        __syncthreads();
    }
    float4 bi = *(const float4*)&bias[n0 + (tx << 2)];
    float bv2[4] = {bi.x, bi.y, bi.z, bi.w};
    #pragma unroll
    for (int i = 0; i < 4; ++i) {
        float4 o;
        o.x = acc[i][0] + bv2[0]; o.y = acc[i][1] + bv2[1];
        o.z = acc[i][2] + bv2[2]; o.w = acc[i][3] + bv2[3];
        if (RELU_OUT) {
            o.x = fmaxf(o.x, 0.f); o.y = fmaxf(o.y, 0.f);
            o.z = fmaxf(o.z, 0.f); o.w = fmaxf(o.w, 0.f);
        }
        *(float4*)&out[((size_t)(h * HW) + w0 + (ty << 2) + i) * COUTC + n0 + (tx << 2)] = o;
    }
}

// ---------------- heads + sigmoid + decode + candidate filter ----------------
__global__ __launch_bounds__(256) void heads_decode_kernel(
    const float* __restrict__ x, const float* __restrict__ w_s, const float* __restrict__ b_s,
    const float* __restrict__ w_b, const float* __restrict__ b_b,
    float4* __restrict__ boxes, unsigned long long* __restrict__ keys,
    int* __restrict__ cnt, int* __restrict__ hist)
{
    __shared__ float xs[4][512];
    __shared__ float outs[4][45];
    int wave = threadIdx.x >> 6;
    int lane = threadIdx.x & 63;
    int pix  = blockIdx.x * 4 + wave;

    const float4* xp = (const float4*)&x[(size_t)pix * COUTC];
    *(float4*)&xs[wave][lane * 4]       = xp[lane];
    *(float4*)&xs[wave][256 + lane * 4] = xp[64 + lane];
    __syncthreads();

    if (lane < 45) {
        const float* wp; int stride; float acc;
        if (lane < 9) { wp = w_s + lane;       stride = 9;  acc = b_s[lane]; }
        else          { wp = w_b + (lane - 9); stride = 36; acc = b_b[lane - 9]; }
        const float* xrow = xs[wave];
        for (int k = 0; k < 512; k += 4) {
            acc = fmaf(xrow[k + 0], wp[(k + 0) * stride], acc);
            acc = fmaf(xrow[k + 1], wp[(k + 1) * stride], acc);
            acc = fmaf(xrow[k + 2], wp[(k + 2) * stride], acc);
            acc = fmaf(xrow[k + 3], wp[(k + 3) * stride], acc);
        }
        outs[wave][lane] = acc;
    }
    __syncthreads();

    if (lane < 9) {
        int h = pix >> 7, w = pix & 127;
        int a = lane;
        float z   = outs[wave][a];
        float dyv = outs[wave][9 + 4 * a + 0];
        float dxv = outs[wave][9 + 4 * a + 1];
        float dhv = outs[wave][9 + 4 * a + 2];
        float dwv = outs[wave][9 + 4 * a + 3];
        float sc  = (a < 3) ? 128.f : ((a < 6) ? 256.f : 512.f);
        int r = a - (a / 3) * 3;
        float ratio = (r == 0) ? 0.5f : ((r == 1) ? 1.f : 2.f);
        float sr = sqrtf(ratio);
        float ahh = sc * sr, aww = sc / sr;
        float acy = ((float)h + 0.5f) * 16.f;
        float acx = ((float)w + 0.5f) * 16.f;
        float cy = fmaf(dyv, ahh, acy);
        float cx = fmaf(dxv, aww, acx);
        float hh = ahh * expf(dhv);
        float ww = aww * expf(dwv);
        float y1 = fminf(fmaxf(cy - 0.5f * hh, 0.f), 2048.f);
        float x1 = fminf(fmaxf(cx - 0.5f * ww, 0.f), 2048.f);
        float y2 = fminf(fmaxf(cy + 0.5f * hh, 0.f), 2048.f);
        float x2 = fminf(fmaxf(cx + 0.5f * ww, 0.f), 2048.f);
        int gi = pix * 9 + a;
        boxes[gi] = make_float4(y1, x1, y2, x2);
        float s = 1.f / (1.f + expf(-z));
        if (s >= 0.5f) {
            unsigned u = __float_as_uint(s);
            unsigned d = 0x3F800000u - u;
            unsigned long long key = ((unsigned long long)d << 18) | (unsigned)gi;
            int p = atomicAdd(cnt, 1);
            keys[p] = key;
            atomicAdd(&hist[d >> 11], 1);
        }
    }
}

__global__ __launch_bounds__(256) void scan_kernel(
    const int* __restrict__ hist, int* __restrict__ base)
{
    __shared__ int buf[256];
    __shared__ int carry;
    int tid = threadIdx.x;
    if (tid == 0) carry = 0;
    __syncthreads();
    for (int c = 0; c < NB; c += 256) {
        int idx = c + tid;
        int v = (idx < NB) ? hist[idx] : 0;
        buf[tid] = v;
        __syncthreads();
        for (int s = 1; s < 256; s <<= 1) {
            int t = (tid >= s) ? buf[tid - s] : 0;
            __syncthreads();
            buf[tid] += t;
            __syncthreads();
        }
        if (idx < NB) base[idx] = carry + buf[tid] - v;
        __syncthreads();
        if (tid == 0) carry += buf[255];
        __syncthreads();
    }
    if (tid == 0) base[NB] = carry;
}

__global__ __launch_bounds__(256) void scatter_kernel(
    const unsigned long long* __restrict__ keys, const int* __restrict__ cnt,
    const int* __restrict__ base, int* __restrict__ cur,
    unsigned long long* __restrict__ skeys)
{
    int i = blockIdx.x * 256 + threadIdx.x;
    if (i < *cnt) {
        unsigned long long k = keys[i];
        int b = (int)(k >> 29);
        int p = base[b] + atomicAdd(&cur[b], 1);
        skeys[p] = k;
    }
}

__global__ __launch_bounds__(256) void nms_kernel(
    unsigned long long* __restrict__ skeys, const int* __restrict__ base,
    const float4* __restrict__ boxes, float* __restrict__ out)
{
    __shared__ float4 sbox[NSEL];
    __shared__ float  sarea[NSEL];
    __shared__ unsigned long long buf[4096];
    __shared__ unsigned long long rmin[256];
    __shared__ int ridx[256];
    __shared__ int selCount;
    __shared__ int flag;

    int tid = threadIdx.x;
    for (int i = tid; i < 1800; i += 256) out[i] = 0.f;
    if (tid == 0) selCount = 0;
    __syncthreads();

    for (int b = 0; b < NB; ++b) {
        if (selCount >= NSEL) break;
        int s0 = base[b];
        int n  = base[b + 1] - s0;
        if (n <= 0) continue;
        bool use_lds = (n <= 4096);
        unsigned long long* bp = use_lds ? buf : (skeys + s0);
        if (use_lds) {
            for (int i = tid; i < n; i += 256) buf[i] = skeys[s0 + i];
        }
        __syncthreads();
        while (true) {
            unsigned long long mv = ~0ull;
            int mi = -1;
            for (int i = tid; i < n; i += 256) {
                unsigned long long v = bp[i];
                if (v < mv) { mv = v; mi = i; }
            }
            rmin[tid] = mv; ridx[tid] = mi;
            __syncthreads();
            for (int s = 128; s > 0; s >>= 1) {
                if (tid < s) {
                    if (rmin[tid + s] < rmin[tid]) {
                        rmin[tid] = rmin[tid + s];
                        ridx[tid] = ridx[tid + s];
                    }
                }
                __syncthreads();
            }
            unsigned long long key = rmin[0];
            if (key == ~0ull) break;
            int sc = selCount;
            if (tid == 0) { bp[ridx[0]] = ~0ull; flag = 0; }
            __syncthreads();
            unsigned gi = (unsigned)(key & 0x3FFFFull);
            float4 cb = boxes[gi];
            float ca = (cb.z - cb.x) * (cb.w - cb.y);
            for (int t = tid; t < sc; t += 256) {
                float4 s4 = sbox[t];
                float iy = fmaxf(0.f, fminf(s4.z, cb.z) - fmaxf(s4.x, cb.x));
                float ix = fmaxf(0.f, fminf(s4.w, cb.w) - fmaxf(s4.y, cb.y));
                float inter = iy * ix;
                float iou = inter / (sarea[t] + ca - inter + 1e-9f);
                if (iou > 0.7f) flag = 1;
            }
            __syncthreads();
            if (flag == 0) {
                if (tid == 0) {
                    int c = selCount;
                    sbox[c] = cb;
                    sarea[c] = ca;
                    out[c * 4 + 0] = cb.x; out[c * 4 + 1] = cb.y;
                    out[c * 4 + 2] = cb.z; out[c * 4 + 3] = cb.w;
                    out[1200 + c] = __uint_as_float(0x3F800000u - (unsigned)(key >> 18));
                    out[1500 + c] = 1.f;
                    selCount = c + 1;
                }
                __syncthreads();
                if (selCount >= NSEL) break;
            }
        }
        __syncthreads();
    }
}

extern "C" void kernel_launch(void* const* d_in, const int* in_sizes, int n_in,
                              void* d_out, int out_size, void* d_ws, size_t ws_size,
                              hipStream_t stream) {
    const float* feat = (const float*)d_in[0];
    const float* w1   = (const float*)d_in[1];
    const float* b1   = (const float*)d_in[2];
    const float* w2   = (const float*)d_in[3];
    const float* b2   = (const float*)d_in[4];
    const float* w_s  = (const float*)d_in[5];
    const float* b_s  = (const float*)d_in[6];
    const float* w_b  = (const float*)d_in[7];
    const float* b_b  = (const float*)d_in[8];
    float* out = (float*)d_out;
    char* ws = (char*)d_ws;

    if (ws_size >= NWS_TOTAL) {
        // ---------- MFMA fp16-split path ----------
        _Float16* a1h = (_Float16*)(ws + NWS_A1H);
        _Float16* a1l = (_Float16*)(ws + NWS_A1L);
        _Float16* w1h = (_Float16*)(ws + NWS_W1H);
        _Float16* w1l = (_Float16*)(ws + NWS_W1L);
        _Float16* a2h = (_Float16*)(ws + NWS_A2H);
        _Float16* a2l = (_Float16*)(ws + NWS_A2L);
        _Float16* w2h = (_Float16*)(ws + NWS_W2H);
        _Float16* w2l = (_Float16*)(ws + NWS_W2L);
        float* x2 = (float*)(ws + NWS_X2);
        float4* boxes = (float4*)(ws + NWS_BOXES);
        unsigned long long* keys  = (unsigned long long*)(ws + NWS_KEYS);
        unsigned long long* skeys = (unsigned long long*)(ws + NWS_SKEYS);
        int* hist = (int*)(ws + NWS_HIST);
        int* cur  = (int*)(ws + NWS_CUR);
        int* cnt  = (int*)(ws + NWS_CNT);
        int* base = (int*)(ws + NWS_BASE);

        hipMemsetAsync(ws + NWS_HIST, 0, (NWS_CNT - NWS_HIST) + 256, stream);
        convert_feat_kernel<<<16900, 256, 0, stream>>>(feat, a1h, a1l);
        convert_w_kernel<9216><<<dim3(288, 16), 256, 0, stream>>>(w1, w1h, w1l);
        convert_w_kernel<4608><<<dim3(144, 16), 256, 0, stream>>>(w2, w2h, w2l);
        zero_pads_kernel<<<516, 256, 0, stream>>>(a2h, a2l);
        conv_mfma_kernel<1024, true ><<<512, 256, 0, stream>>>(a1h, a1l, w1h, w1l, b1, a2h, a2l, nullptr);
        conv_mfma_kernel< 512, false><<<512, 256, 0, stream>>>(a2h, a2l, w2h, w2l, b2, nullptr, nullptr, x2);
        heads_decode_kernel<<<4096, 256, 0, stream>>>(x2, w_s, b_s, w_b, b_b, boxes, keys, cnt, hist);
        scan_kernel<<<1, 256, 0, stream>>>(hist, base);
        scatter_kernel<<<576, 256, 0, stream>>>(keys, cnt, base, cur, skeys);
        nms_kernel<<<1, 256, 0, stream>>>(skeys, base, boxes, out);
    } else {
        // ---------- fallback fp32 path ----------
        float* x1 = (float*)(ws + WS_X1);
        float* x2 = (float*)(ws + WS_X2);
        float4* boxes = (float4*)(ws + WS_BOXES);
        unsigned long long* keys  = (unsigned long long*)(ws + WS_KEYS);
        unsigned long long* skeys = (unsigned long long*)(ws + WS_SKEYS);
        int* hist = (int*)(ws + WS_HIST);
        int* cur  = (int*)(ws + WS_CUR);
        int* cnt  = (int*)(ws + WS_CNT);
        int* base = (int*)(ws + WS_BASE);

        hipMemsetAsync(ws + WS_HIST, 0, (WS_CNT - WS_HIST) + 256, stream);
        conv3x3_kernel<1024, true,  true ><<<2048, 256, 0, stream>>>(feat, w1, b1, x1);
        conv3x3_kernel< 512, false, false><<<2048, 256, 0, stream>>>(x1,   w2, b2, x2);
        heads_decode_kernel<<<4096, 256, 0, stream>>>(x2, w_s, b_s, w_b, b_b, boxes, keys, cnt, hist);
        scan_kernel<<<1, 256, 0, stream>>>(hist, base);
        scatter_kernel<<<576, 256, 0, stream>>>(keys, cnt, base, cur, skeys);
        nms_kernel<<<1, 256, 0, stream>>>(skeys, base, boxes, out);
    }
}

// Round 3
// 1398.214 us; speedup vs baseline: 3.1368x; 1.1925x over previous
//
#include <hip/hip_runtime.h>

#define HW 128
#define COUTC 512
#define NB 4097
#define NSEL 300
#define BUFN 4096

typedef _Float16 half8 __attribute__((ext_vector_type(8)));
typedef _Float16 half4v __attribute__((ext_vector_type(4)));
typedef float floatx4 __attribute__((ext_vector_type(4)));

// ================= new ws layout (bytes) =================
#define NWS_A1H   ((size_t)0)            // 130*130*1024*2 = 34,611,200
#define NWS_A1L   ((size_t)34611200)
#define NWS_W1H   ((size_t)69222400)     // 512*9216*2 = 9,437,184
#define NWS_W1L   ((size_t)78659584)
#define NWS_A2H   ((size_t)88096768)     // 130*130*512*2 = 17,305,600
#define NWS_A2L   ((size_t)105402368)
#define NWS_W2H   ((size_t)122707968)    // 512*4608*2 = 4,718,592
#define NWS_W2L   ((size_t)127426560)
#define NWS_X2    ((size_t)132145152)    // 16384*512*4 = 33,554,432
#define NWS_BOXES ((size_t)165699584)    // 147456*16
#define NWS_KEYS  ((size_t)168058880)    // 147456*8
#define NWS_SKEYS ((size_t)169238528)
#define NWS_HIST  ((size_t)170418176)    // 4097*4 pad 16640
#define NWS_CUR   ((size_t)170434816)
#define NWS_CNT   ((size_t)170451456)    // pad 256
#define NWS_BASE  ((size_t)170451712)    // 4098*4
#define NWS_TOTAL ((size_t)170468352)

// ================= old (fallback) ws layout =================
#define WS_X1     ((size_t)0)
#define WS_X2     ((size_t)33554432)
#define WS_BOXES  ((size_t)67108864)
#define WS_KEYS   ((size_t)69468160)
#define WS_SKEYS  ((size_t)70647808)
#define WS_HIST   ((size_t)71827456)
#define WS_CUR    ((size_t)71844096)
#define WS_CNT    ((size_t)71860736)
#define WS_BASE   ((size_t)71860992)

__device__ __forceinline__ void glds16(const void* g, void* l) {
    __builtin_amdgcn_global_load_lds(
        (const __attribute__((address_space(1))) void*)g,
        (__attribute__((address_space(3))) void*)l, 16, 0, 0);
}

// ---------------- feature convert: relu + fp16 hi/lo split into padded planes ----------------
__global__ __launch_bounds__(256) void convert_feat_kernel(
    const float* __restrict__ feat, _Float16* __restrict__ ah, _Float16* __restrict__ al)
{
    int p  = blockIdx.x;            // 0..16899 padded pixel
    int pr = p / 130, pc = p % 130;
    int c  = threadIdx.x * 4;
    half4v vh = (half4v)(_Float16)0.f, vl = (half4v)(_Float16)0.f;
    if (pr != 0 && pr != 129 && pc != 0 && pc != 129) {
        float4 v = *(const float4*)&feat[(size_t)(((pr - 1) * HW) + (pc - 1)) * 1024 + c];
        float f[4] = {v.x, v.y, v.z, v.w};
        #pragma unroll
        for (int i = 0; i < 4; ++i) {
            float x = fmaxf(f[i], 0.f);
            _Float16 hi = (_Float16)x;
            vh[i] = hi;
            vl[i] = (_Float16)(x - (float)hi);
        }
    }
    *(half4v*)&ah[(size_t)p * 1024 + c] = vh;
    *(half4v*)&al[(size_t)p * 1024 + c] = vl;
}

// ---------------- weight convert: transpose [K][512] -> [512][K], scale x64, split hi/lo ----------------
template<int K>
__global__ __launch_bounds__(256) void convert_w_kernel(
    const float* __restrict__ w, _Float16* __restrict__ wh, _Float16* __restrict__ wl)
{
    __shared__ float t[32][33];
    int k0 = blockIdx.x * 32, oc0 = blockIdx.y * 32;
    int tx = threadIdx.x & 31, ty = threadIdx.x >> 5;   // ty 0..7
    #pragma unroll
    for (int r = 0; r < 32; r += 8)
        t[ty + r][tx] = w[(size_t)(k0 + ty + r) * COUTC + oc0 + tx] * 64.f;
    __syncthreads();
    #pragma unroll
    for (int r = 0; r < 32; r += 8) {
        int oc = oc0 + ty + r, k = k0 + tx;
        float v = t[tx][ty + r];
        _Float16 hi = (_Float16)v;
        wh[(size_t)oc * K + k] = hi;
        wl[(size_t)oc * K + k] = (_Float16)(v - (float)hi);
    }
}

// ---------------- zero the pad ring of a 130x130x512 plane pair ----------------
__global__ __launch_bounds__(256) void zero_pads_kernel(_Float16* ah, _Float16* al)
{
    int i = blockIdx.x;  // 0..515
    int pr, pc;
    if (i < 130)      { pr = 0;        pc = i; }
    else if (i < 260) { pr = 129;      pc = i - 130; }
    else if (i < 388) { pr = i - 259;  pc = 0; }     // rows 1..128
    else              { pr = i - 387;  pc = 129; }
    int p = pr * 130 + pc;
    int c = threadIdx.x * 2;
    *(unsigned*)&ah[(size_t)p * 512 + c] = 0u;
    *(unsigned*)&al[(size_t)p * 512 + c] = 0u;
}

// ---------------- conv 3x3 via fp16-split MFMA implicit GEMM ----------------
template<int CIN, bool SPLIT_OUT>
__global__ __launch_bounds__(256) void conv_mfma_kernel(
    const _Float16* __restrict__ ah, const _Float16* __restrict__ al,  // padded [130*130][CIN]
    const _Float16* __restrict__ wh, const _Float16* __restrict__ wl,  // [512][9*CIN]
    const float* __restrict__ bias,
    _Float16* __restrict__ oh, _Float16* __restrict__ ol,  // SPLIT_OUT: padded [130*130][512]
    float* __restrict__ of)                                 // !SPLIT_OUT: [16384][512]
{
    constexpr int K9 = 9 * CIN;
    __shared__ __align__(16) _Float16 lds[16384];  // AHI 0, ALO 4096, BHI 8192, BLO 12288 (halves)

    int bx = blockIdx.x;
    int h  = bx & 127;
    int n0 = (bx >> 7) << 7;

    int tid  = threadIdx.x;
    int wave = tid >> 6;
    int lane = tid & 63;

    int sp = lane >> 2;            // 0..15
    int kq = (lane & 3) << 3;      // halves: 0,8,16,24

    int aoff0 = (32 * wave + sp) * CIN + kq;
    int aoff1 = aoff0 + 16 * CIN;
    int boff0 = (n0 + 32 * wave + sp) * K9 + kq;
    int boff1 = boff0 + 16 * K9;

    _Float16* dA0 = lds +        1024 * wave;
    _Float16* dA1 = dA0 + 512;
    _Float16* dL0 = lds + 4096 + 1024 * wave;
    _Float16* dL1 = dL0 + 512;
    _Float16* dB0 = lds + 8192 + 1024 * wave;
    _Float16* dB1 = dB0 + 512;
    _Float16* dC0 = lds + 12288 + 1024 * wave;
    _Float16* dC1 = dC0 + 512;

    int fr = lane & 15;
    int fq = lane >> 4;
    int wm = wave & 1, wn = wave >> 1;
    const _Float16* rAh = lds +         (64 * wm + fr) * 32 + fq * 8;
    const _Float16* rAl = rAh + 4096;
    const _Float16* rBh = lds + 8192 + (64 * wn + fr) * 32 + fq * 8;
    const _Float16* rBl = rBh + 4096;

    floatx4 acc[4][4];
    #pragma unroll
    for (int i = 0; i < 4; ++i)
        #pragma unroll
        for (int j = 0; j < 4; ++j)
            acc[i][j] = (floatx4){0.f, 0.f, 0.f, 0.f};

    #pragma unroll
    for (int tap = 0; tap < 9; ++tap) {
        int dy = tap / 3 - 1, dx = tap % 3 - 1;
        const _Float16* gAh = ah + (size_t)((h + dy + 1) * 130 + (dx + 1)) * CIN;
        const _Float16* gAl = al + (size_t)((h + dy + 1) * 130 + (dx + 1)) * CIN;
        const _Float16* gBh = wh + (size_t)tap * CIN;
        const _Float16* gBl = wl + (size_t)tap * CIN;

        for (int kc = 0; kc < CIN; kc += 32) {
            glds16(gAh + aoff0 + kc, dA0);
            glds16(gAh + aoff1 + kc, dA1);
            glds16(gAl + aoff0 + kc, dL0);
            glds16(gAl + aoff1 + kc, dL1);
            glds16(gBh + boff0 + kc, dB0);
            glds16(gBh + boff1 + kc, dB1);
            glds16(gBl + boff0 + kc, dC0);
            glds16(gBl + boff1 + kc, dC1);
            __syncthreads();

            half8 fah[4], fal[4], fbh[4], fbl[4];
            #pragma unroll
            for (int i = 0; i < 4; ++i) {
                fah[i] = *(const half8*)(rAh + i * 512);
                fal[i] = *(const half8*)(rAl + i * 512);
                fbh[i] = *(const half8*)(rBh + i * 512);
                fbl[i] = *(const half8*)(rBl + i * 512);
            }
            #pragma unroll
            for (int i = 0; i < 4; ++i)
                #pragma unroll
                for (int j = 0; j < 4; ++j)
                    acc[i][j] = __builtin_amdgcn_mfma_f32_16x16x32_f16(fah[i], fbh[j], acc[i][j], 0, 0, 0);
            #pragma unroll
            for (int i = 0; i < 4; ++i)
                #pragma unroll
                for (int j = 0; j < 4; ++j)
                    acc[i][j] = __builtin_amdgcn_mfma_f32_16x16x32_f16(fah[i], fbl[j], acc[i][j], 0, 0, 0);
            #pragma unroll
            for (int i = 0; i < 4; ++i)
                #pragma unroll
                for (int j = 0; j < 4; ++j)
                    acc[i][j] = __builtin_amdgcn_mfma_f32_16x16x32_f16(fal[i], fbh[j], acc[i][j], 0, 0, 0);
            __syncthreads();
        }
    }

    const float scale = 1.f / 64.f;
    int em = 64 * wm + fq * 4;
    int en = 64 * wn + fr;
    #pragma unroll
    for (int j = 0; j < 4; ++j) {
        int oc = n0 + en + 16 * j;
        float b = bias[oc];
        #pragma unroll
        for (int i = 0; i < 4; ++i) {
            #pragma unroll
            for (int r = 0; r < 4; ++r) {
                int w = em + 16 * i + r;
                float v = fmaf(acc[i][j][r], scale, b);
                if (SPLIT_OUT) {
                    v = fmaxf(v, 0.f);
                    _Float16 hi = (_Float16)v;
                    size_t o = ((size_t)(h + 1) * 130 + (w + 1)) * COUTC + oc;
                    oh[o] = hi;
                    ol[o] = (_Float16)(v - (float)hi);
                } else {
                    of[((size_t)h * HW + w) * COUTC + oc] = v;
                }
            }
        }
    }
}

// ---------------- OLD fp32 conv (fallback when ws is small) ----------------
template<int CIN, bool RELU_IN, bool RELU_OUT>
__global__ __launch_bounds__(256) void conv3x3_kernel(
    const float* __restrict__ in, const float* __restrict__ wgt,
    const float* __restrict__ bias, float* __restrict__ out)
{
    __shared__ float As[32][68];
    __shared__ float Bs[32][64];
    int bx = blockIdx.x;
    int mtile = bx & 255, ntile = bx >> 8;
    int h = mtile >> 1, w0 = (mtile & 1) << 6, n0 = ntile << 6;
    int tid = threadIdx.x, ty = tid >> 4, tx = tid & 15;
    float acc[4][4] = {{0.f}};
    const int KTOT = 9 * CIN;
    for (int k0 = 0; k0 < KTOT; k0 += 32) {
        int tap = k0 / CIN, icb = k0 % CIN;
        int dy = tap / 3 - 1, dx = tap % 3 - 1;
        int row = h + dy;
        bool rowok = ((unsigned)row < HW);
        {
            int pix = tid >> 3, cs = (tid & 7) << 2;
            #pragma unroll
            for (int p = 0; p < 2; ++p) {
                int px = pix + p * 32;
                int wcol = w0 + px + dx;
                float4 v = make_float4(0.f, 0.f, 0.f, 0.f);
                if (rowok && (unsigned)wcol < HW) {
                    v = *(const float4*)&in[((size_t)row * HW + wcol) * CIN + icb + cs];
                    if (RELU_IN) {
                        v.x = fmaxf(v.x, 0.f); v.y = fmaxf(v.y, 0.f);
                        v.z = fmaxf(v.z, 0.f); v.w = fmaxf(v.w, 0.f);
                    }
                }
                As[cs + 0][px] = v.x; As[cs + 1][px] = v.y;
                As[cs + 2][px] = v.z; As[cs + 3][px] = v.w;
            }
        }
        {
            int kr = tid >> 4, nc = (tid & 15) << 2;
            #pragma unroll
            for (int p = 0; p < 2; ++p) {
                int k = kr + p * 16;
                *(float4*)&Bs[k][nc] = *(const float4*)&wgt[(size_t)(k0 + k) * COUTC + n0 + nc];
            }
        }
        __syncthreads();
        #pragma unroll
        for (int kk = 0; kk < 32; ++kk) {
            float4 a = *(const float4*)&As[kk][ty << 2];
            float4 b = *(const float4*)&Bs[kk][tx << 2];
            float av[4] = {a.x, a.y, a.z, a.w};
            float bv[4] = {b.x, b.y, b.z, b.w};
            #pragma unroll
            for (int i = 0; i < 4; ++i)
                #pragma unroll
                for (int j = 0; j < 4; ++j)
                    acc[i][j] = fmaf(av[i], bv[j], acc[i][j]);
        }
        __syncthreads();
    }
    float4 bi = *(const float4*)&bias[n0 + (tx << 2)];
    float bv2[4] = {bi.x, bi.y, bi.z, bi.w};
    #pragma unroll
    for (int i = 0; i < 4; ++i) {
        float4 o;
        o.x = acc[i][0] + bv2[0]; o.y = acc[i][1] + bv2[1];
        o.z = acc[i][2] + bv2[2]; o.w = acc[i][3] + bv2[3];
        if (RELU_OUT) {
            o.x = fmaxf(o.x, 0.f); o.y = fmaxf(o.y, 0.f);
            o.z = fmaxf(o.z, 0.f); o.w = fmaxf(o.w, 0.f);
        }
        *(float4*)&out[((size_t)(h * HW) + w0 + (ty << 2) + i) * COUTC + n0 + (tx << 2)] = o;
    }
}

// ---------------- heads + sigmoid + decode + candidate filter ----------------
__global__ __launch_bounds__(256) void heads_decode_kernel(
    const float* __restrict__ x, const float* __restrict__ w_s, const float* __restrict__ b_s,
    const float* __restrict__ w_b, const float* __restrict__ b_b,
    float4* __restrict__ boxes, unsigned long long* __restrict__ keys,
    int* __restrict__ cnt, int* __restrict__ hist)
{
    __shared__ float xs[4][512];
    __shared__ float outs[4][45];
    int wave = threadIdx.x >> 6;
    int lane = threadIdx.x & 63;
    int pix  = blockIdx.x * 4 + wave;

    const float4* xp = (const float4*)&x[(size_t)pix * COUTC];
    *(float4*)&xs[wave][lane * 4]       = xp[lane];
    *(float4*)&xs[wave][256 + lane * 4] = xp[64 + lane];
    __syncthreads();

    if (lane < 45) {
        const float* wp; int stride; float acc;
        if (lane < 9) { wp = w_s + lane;       stride = 9;  acc = b_s[lane]; }
        else          { wp = w_b + (lane - 9); stride = 36; acc = b_b[lane - 9]; }
        const float* xrow = xs[wave];
        for (int k = 0; k < 512; k += 4) {
            acc = fmaf(xrow[k + 0], wp[(k + 0) * stride], acc);
            acc = fmaf(xrow[k + 1], wp[(k + 1) * stride], acc);
            acc = fmaf(xrow[k + 2], wp[(k + 2) * stride], acc);
            acc = fmaf(xrow[k + 3], wp[(k + 3) * stride], acc);
        }
        outs[wave][lane] = acc;
    }
    __syncthreads();

    if (lane < 9) {
        int h = pix >> 7, w = pix & 127;
        int a = lane;
        float z   = outs[wave][a];
        float dyv = outs[wave][9 + 4 * a + 0];
        float dxv = outs[wave][9 + 4 * a + 1];
        float dhv = outs[wave][9 + 4 * a + 2];
        float dwv = outs[wave][9 + 4 * a + 3];
        float sc  = (a < 3) ? 128.f : ((a < 6) ? 256.f : 512.f);
        int r = a - (a / 3) * 3;
        float ratio = (r == 0) ? 0.5f : ((r == 1) ? 1.f : 2.f);
        float sr = sqrtf(ratio);
        float ahh = sc * sr, aww = sc / sr;
        float acy = ((float)h + 0.5f) * 16.f;
        float acx = ((float)w + 0.5f) * 16.f;
        float cy = fmaf(dyv, ahh, acy);
        float cx = fmaf(dxv, aww, acx);
        float hh = ahh * expf(dhv);
        float ww = aww * expf(dwv);
        float y1 = fminf(fmaxf(cy - 0.5f * hh, 0.f), 2048.f);
        float x1 = fminf(fmaxf(cx - 0.5f * ww, 0.f), 2048.f);
        float y2 = fminf(fmaxf(cy + 0.5f * hh, 0.f), 2048.f);
        float x2 = fminf(fmaxf(cx + 0.5f * ww, 0.f), 2048.f);
        int gi = pix * 9 + a;
        boxes[gi] = make_float4(y1, x1, y2, x2);
        float s = 1.f / (1.f + expf(-z));
        if (s >= 0.5f) {
            unsigned u = __float_as_uint(s);
            unsigned d = 0x3F800000u - u;
            unsigned long long key = ((unsigned long long)d << 18) | (unsigned)gi;
            int p = atomicAdd(cnt, 1);
            keys[p] = key;
            atomicAdd(&hist[d >> 11], 1);
        }
    }
}

__global__ __launch_bounds__(256) void scan_kernel(
    const int* __restrict__ hist, int* __restrict__ base)
{
    __shared__ int buf[256];
    __shared__ int carry;
    int tid = threadIdx.x;
    if (tid == 0) carry = 0;
    __syncthreads();
    for (int c = 0; c < NB; c += 256) {
        int idx = c + tid;
        int v = (idx < NB) ? hist[idx] : 0;
        buf[tid] = v;
        __syncthreads();
        for (int s = 1; s < 256; s <<= 1) {
            int t = (tid >= s) ? buf[tid - s] : 0;
            __syncthreads();
            buf[tid] += t;
            __syncthreads();
        }
        if (idx < NB) base[idx] = carry + buf[tid] - v;
        __syncthreads();
        if (tid == 0) carry += buf[255];
        __syncthreads();
    }
    if (tid == 0) base[NB] = carry;
}

__global__ __launch_bounds__(256) void scatter_kernel(
    const unsigned long long* __restrict__ keys, const int* __restrict__ cnt,
    const int* __restrict__ base, int* __restrict__ cur,
    unsigned long long* __restrict__ skeys)
{
    int i = blockIdx.x * 256 + threadIdx.x;
    if (i < *cnt) {
        unsigned long long k = keys[i];
        int b = (int)(k >> 29);
        int p = base[b] + atomicAdd(&cur[b], 1);
        skeys[p] = k;
    }
}

// ---------------- greedy NMS: bucket-ordered rank-sort + single-wave walk ----------------
__global__ __launch_bounds__(256) void nms_kernel(
    const unsigned long long* __restrict__ skeys, const int* __restrict__ base,
    const float4* __restrict__ boxes, float* __restrict__ out)
{
    __shared__ int sbase[NB + 1];                 // 16392 B
    __shared__ unsigned long long buf[BUFN];      // unsorted bucket keys (32 KB)
    __shared__ unsigned long long srt[BUFN];      // rank-sorted window    (32 KB)
    __shared__ float4 bbox[1024];                 // gathered boxes for walk chunk (16 KB)
    __shared__ float4 sbox[NSEL];
    __shared__ float  sarea[NSEL];

    int tid = threadIdx.x;
    for (int i = tid; i < 1800; i += 256) out[i] = 0.f;
    for (int i = tid; i <= NB; i += 256) sbase[i] = base[i];
    __syncthreads();
    if (tid >= 64) return;                        // single-wave from here: NO barriers below
    int lane = tid;

    int sel = 0;
    for (int b = 0; b < NB && sel < NSEL; ++b) {
        int s0 = sbase[b];
        int n  = sbase[b + 1] - s0;
        if (n <= 0) continue;

        const unsigned long long* src;
        if (n <= BUFN) {
            for (int i = lane; i < n; i += 64) buf[i] = skeys[s0 + i];
            src = buf;
        } else {
            src = skeys + s0;                     // huge bucket: rank over global (rare/never)
        }

        for (int ps = 0; ps < n && sel < NSEL; ps += BUFN) {
            int m = n - ps; if (m > BUFN) m = BUFN;
            // exact rank sort (keys unique: unique gi); window [ps, ps+m)
            for (int i = lane; i < n; i += 64) {
                unsigned long long k = src[i];
                int r = 0;
                for (int j = 0; j < n; ++j) r += (src[j] < k) ? 1 : 0;
                if (r >= ps && r < ps + m) srt[r - ps] = k;
            }
            // walk in 1024-candidate chunks with LDS box gather
            for (int cs = 0; cs < m && sel < NSEL; cs += 1024) {
                int cm = m - cs; if (cm > 1024) cm = 1024;
                for (int i = lane; i < cm; i += 64) {
                    unsigned gi = (unsigned)(srt[cs + i] & 0x3FFFFull);
                    bbox[i] = boxes[gi];
                }
                for (int i = 0; i < cm && sel < NSEL; ++i) {
                    float4 cb = bbox[i];
                    float ca = (cb.z - cb.x) * (cb.w - cb.y);
                    int sup = 0;
                    for (int t = lane; t < sel; t += 64) {
                        float4 s4 = sbox[t];
                        float iy = fmaxf(0.f, fminf(s4.z, cb.z) - fmaxf(s4.x, cb.x));
                        float ix = fmaxf(0.f, fminf(s4.w, cb.w) - fmaxf(s4.y, cb.y));
                        float inter = iy * ix;
                        float iou = inter / (sarea[t] + ca - inter + 1e-9f);
                        if (iou > 0.7f) sup = 1;
                    }
                    if (__ballot(sup) == 0ull) {
                        if (lane == 0) {
                            sbox[sel]  = cb;
                            sarea[sel] = ca;
                            out[sel * 4 + 0] = cb.x;
                            out[sel * 4 + 1] = cb.y;
                            out[sel * 4 + 2] = cb.z;
                            out[sel * 4 + 3] = cb.w;
                            unsigned long long key = srt[cs + i];
                            out[1200 + sel] = __uint_as_float(0x3F800000u - (unsigned)(key >> 18));
                            out[1500 + sel] = 1.f;
                        }
                        sel++;
                    }
                }
            }
        }
    }
}

extern "C" void kernel_launch(void* const* d_in, const int* in_sizes, int n_in,
                              void* d_out, int out_size, void* d_ws, size_t ws_size,
                              hipStream_t stream) {
    const float* feat = (const float*)d_in[0];
    const float* w1   = (const float*)d_in[1];
    const float* b1   = (const float*)d_in[2];
    const float* w2   = (const float*)d_in[3];
    const float* b2   = (const float*)d_in[4];
    const float* w_s  = (const float*)d_in[5];
    const float* b_s  = (const float*)d_in[6];
    const float* w_b  = (const float*)d_in[7];
    const float* b_b  = (const float*)d_in[8];
    float* out = (float*)d_out;
    char* ws = (char*)d_ws;

    if (ws_size >= NWS_TOTAL) {
        _Float16* a1h = (_Float16*)(ws + NWS_A1H);
        _Float16* a1l = (_Float16*)(ws + NWS_A1L);
        _Float16* w1h = (_Float16*)(ws + NWS_W1H);
        _Float16* w1l = (_Float16*)(ws + NWS_W1L);
        _Float16* a2h = (_Float16*)(ws + NWS_A2H);
        _Float16* a2l = (_Float16*)(ws + NWS_A2L);
        _Float16* w2h = (_Float16*)(ws + NWS_W2H);
        _Float16* w2l = (_Float16*)(ws + NWS_W2L);
        float* x2 = (float*)(ws + NWS_X2);
        float4* boxes = (float4*)(ws + NWS_BOXES);
        unsigned long long* keys  = (unsigned long long*)(ws + NWS_KEYS);
        unsigned long long* skeys = (unsigned long long*)(ws + NWS_SKEYS);
        int* hist = (int*)(ws + NWS_HIST);
        int* cur  = (int*)(ws + NWS_CUR);
        int* cnt  = (int*)(ws + NWS_CNT);
        int* base = (int*)(ws + NWS_BASE);

        hipMemsetAsync(ws + NWS_HIST, 0, (NWS_CNT - NWS_HIST) + 256, stream);
        convert_feat_kernel<<<16900, 256, 0, stream>>>(feat, a1h, a1l);
        convert_w_kernel<9216><<<dim3(288, 16), 256, 0, stream>>>(w1, w1h, w1l);
        convert_w_kernel<4608><<<dim3(144, 16), 256, 0, stream>>>(w2, w2h, w2l);
        zero_pads_kernel<<<516, 256, 0, stream>>>(a2h, a2l);
        conv_mfma_kernel<1024, true ><<<512, 256, 0, stream>>>(a1h, a1l, w1h, w1l, b1, a2h, a2l, nullptr);
        conv_mfma_kernel< 512, false><<<512, 256, 0, stream>>>(a2h, a2l, w2h, w2l, b2, nullptr, nullptr, x2);
        heads_decode_kernel<<<4096, 256, 0, stream>>>(x2, w_s, b_s, w_b, b_b, boxes, keys, cnt, hist);
        scan_kernel<<<1, 256, 0, stream>>>(hist, base);
        scatter_kernel<<<576, 256, 0, stream>>>(keys, cnt, base, cur, skeys);
        nms_kernel<<<1, 256, 0, stream>>>(skeys, base, boxes, out);
    } else {
        float* x1 = (float*)(ws + WS_X1);
        float* x2 = (float*)(ws + WS_X2);
        float4* boxes = (float4*)(ws + WS_BOXES);
        unsigned long long* keys  = (unsigned long long*)(ws + WS_KEYS);
        unsigned long long* skeys = (unsigned long long*)(ws + WS_SKEYS);
        int* hist = (int*)(ws + WS_HIST);
        int* cur  = (int*)(ws + WS_CUR);
        int* cnt  = (int*)(ws + WS_CNT);
        int* base = (int*)(ws + WS_BASE);

        hipMemsetAsync(ws + WS_HIST, 0, (WS_CNT - WS_HIST) + 256, stream);
        conv3x3_kernel<1024, true,  true ><<<2048, 256, 0, stream>>>(feat, w1, b1, x1);
        conv3x3_kernel< 512, false, false><<<2048, 256, 0, stream>>>(x1,   w2, b2, x2);
        heads_decode_kernel<<<4096, 256, 0, stream>>>(x2, w_s, b_s, w_b, b_b, boxes, keys, cnt, hist);
        scan_kernel<<<1, 256, 0, stream>>>(hist, base);
        scatter_kernel<<<576, 256, 0, stream>>>(keys, cnt, base, cur, skeys);
        nms_kernel<<<1, 256, 0, stream>>>(skeys, base, boxes, out);
    }
}

// Round 4
// 1261.318 us; speedup vs baseline: 3.4773x; 1.1085x over previous
//
#include <hip/hip_runtime.h>

#define HW 128
#define COUTC 512
#define NB 4097
#define NSEL 300
#define T_TOP 16384
#define TW 256          // words per mask row = T_TOP/64

typedef _Float16 half8 __attribute__((ext_vector_type(8)));
typedef _Float16 half4v __attribute__((ext_vector_type(4)));
typedef float floatx4 __attribute__((ext_vector_type(4)));

// ================= fast-path ws layout (bytes) =================
#define NWS_A1H   ((size_t)0)            // 130*130*1024*2 = 34,611,200  (dead after conv1 -> MSK)
#define NWS_A1L   ((size_t)34611200)     // (dead after conv1 -> CBOX/CAREA)
#define NWS_W1H   ((size_t)69222400)
#define NWS_W1L   ((size_t)78659584)
#define NWS_A2H   ((size_t)88096768)
#define NWS_A2L   ((size_t)105402368)
#define NWS_W2H   ((size_t)122707968)
#define NWS_W2L   ((size_t)127426560)
#define NWS_X2    ((size_t)132145152)
#define NWS_BOXES ((size_t)165699584)
#define NWS_KEYS  ((size_t)168058880)    // scatter input; reused as sorted keys (sk2)
#define NWS_SKEYS ((size_t)169238528)
#define NWS_HIST  ((size_t)170418176)
#define NWS_CUR   ((size_t)170434816)
#define NWS_CNT   ((size_t)170451456)
#define NWS_BASE  ((size_t)170451712)
#define NWS_TOTAL ((size_t)170468352)

// ================= fallback ws layout =================
#define WS_X1     ((size_t)0)
#define WS_X2     ((size_t)33554432)
#define WS_BOXES  ((size_t)67108864)
#define WS_KEYS   ((size_t)69468160)
#define WS_SKEYS  ((size_t)70647808)
#define WS_HIST   ((size_t)71827456)
#define WS_CUR    ((size_t)71844096)
#define WS_CNT    ((size_t)71860736)
#define WS_BASE   ((size_t)71860992)

__device__ __forceinline__ void glds16(const void* g, void* l) {
    __builtin_amdgcn_global_load_lds(
        (const __attribute__((address_space(1))) void*)g,
        (__attribute__((address_space(3))) void*)l, 16, 0, 0);
}

// Activation global layout (per padded row pr): [chunk(CIN/32)][sub(4)][pc(130)][8ch]
//   halves: rowstride = CIN*130, chunkstride = 4160, substride = 1040, pixstride = 8
// Weight global layout (per tap): [chunk(CIN/32)][sub(4)][oc(512)][8ch]
//   halves: tapstride = CIN*512, chunkstride = 16384, substride = 4096, ocstride = 8

// ---------------- feature convert: relu + fp16 hi/lo split, swizzled layout ----------------
__global__ __launch_bounds__(256) void convert_feat_kernel(
    const float* __restrict__ feat, _Float16* __restrict__ ah, _Float16* __restrict__ al)
{
    int p  = blockIdx.x;            // 0..16899 padded pixel
    int pr = p / 130, pc = p % 130;
    int c  = threadIdx.x * 4;
    half4v vh = (half4v)(_Float16)0.f, vl = (half4v)(_Float16)0.f;
    if (pr != 0 && pr != 129 && pc != 0 && pc != 129) {
        float4 v = *(const float4*)&feat[(size_t)(((pr - 1) * HW) + (pc - 1)) * 1024 + c];
        float f[4] = {v.x, v.y, v.z, v.w};
        #pragma unroll
        for (int i = 0; i < 4; ++i) {
            float x = fmaxf(f[i], 0.f);
            _Float16 hi = (_Float16)x;
            vh[i] = hi;
            vl[i] = (_Float16)(x - (float)hi);
        }
    }
    size_t o = (size_t)pr * 133120 + (size_t)(c >> 5) * 4160
             + (size_t)((c >> 3) & 3) * 1040 + (size_t)pc * 8 + (c & 7);
    *(half4v*)&ah[o] = vh;
    *(half4v*)&al[o] = vl;
}

// ---------------- weight convert: scale x64, split hi/lo, swizzled layout ----------------
template<int CIN>
__global__ __launch_bounds__(256) void convert_w_kernel(
    const float* __restrict__ w, _Float16* __restrict__ wh, _Float16* __restrict__ wl)
{
    constexpr int NU = CIN / 8;
    int gid = blockIdx.x * 256 + threadIdx.x;
    int oc = gid & 511;
    int rest = gid >> 9;
    int u = rest & (NU - 1);
    int tap = rest / NU;
    if (tap >= 9) return;
    int k0 = u * 8;
    half8 vh, vl;
    #pragma unroll
    for (int j = 0; j < 8; ++j) {
        float v = w[((size_t)tap * CIN + k0 + j) * 512 + oc] * 64.f;
        _Float16 hi = (_Float16)v;
        vh[j] = hi;
        vl[j] = (_Float16)(v - (float)hi);
    }
    size_t o = (size_t)tap * CIN * 512 + (size_t)(k0 >> 5) * 16384
             + (size_t)((k0 >> 3) & 3) * 4096 + (size_t)oc * 8;
    *(half8*)(wh + o) = vh;
    *(half8*)(wl + o) = vl;
}

// ---------------- zero pad ring of the 130x130x512 swizzled plane pair ----------------
__global__ __launch_bounds__(256) void zero_pads_kernel(_Float16* ah, _Float16* al)
{
    int i = blockIdx.x;  // 0..515
    int pr, pc;
    if (i < 130)      { pr = 0;        pc = i; }
    else if (i < 260) { pr = 129;      pc = i - 130; }
    else if (i < 388) { pr = i - 259;  pc = 0; }
    else              { pr = i - 387;  pc = 129; }
    int t = threadIdx.x;
    if (t >= 128) return;
    _Float16* dst = (t & 64) ? al : ah;
    int u = t & 63;                      // (chunk, sub)
    size_t o = (size_t)pr * 66560 + (size_t)(u >> 2) * 4160 + (size_t)(u & 3) * 1040 + (size_t)pc * 8;
    *(float4*)(dst + o) = make_float4(0.f, 0.f, 0.f, 0.f);
}

// ---------------- conv 3x3 via fp16-split MFMA, conflict-free LDS ----------------
template<int CIN, bool SPLIT_OUT>
__global__ __launch_bounds__(256) void conv_mfma_kernel(
    const _Float16* __restrict__ ah, const _Float16* __restrict__ al,
    const _Float16* __restrict__ wh, const _Float16* __restrict__ wl,
    const float* __restrict__ bias,
    _Float16* __restrict__ oh, _Float16* __restrict__ ol,
    float* __restrict__ of)
{
    constexpr int ROWSTR = CIN * 130;
    constexpr int TAPW   = CIN * 512;
    __shared__ __align__(16) _Float16 lds[16384]; // AHI 0, ALO 4096, BHI 8192, BLO 12288 (halves)

    int bx = blockIdx.x;
    int h  = bx & 127;
    int n0 = (bx >> 7) << 7;

    int tid  = threadIdx.x;
    int wave = tid >> 6;
    int lane = tid & 63;
    int fr = lane & 15;
    int fq = lane >> 4;

    // staging source offsets (halves)
    int aoff0 = fq * 1040 + (32 * wave + fr) * 8;
    int aoff1 = aoff0 + 128;
    int boff0 = fq * 4096 + (n0 + 32 * wave + fr) * 8;
    int boff1 = boff0 + 128;

    _Float16* dA0 = lds +         (2 * wave) * 512;
    _Float16* dA1 = lds +         (2 * wave + 1) * 512;
    _Float16* dL0 = lds + 4096 +  (2 * wave) * 512;
    _Float16* dL1 = lds + 4096 +  (2 * wave + 1) * 512;
    _Float16* dB0 = lds + 8192 +  (2 * wave) * 512;
    _Float16* dB1 = lds + 8192 +  (2 * wave + 1) * 512;
    _Float16* dC0 = lds + 12288 + (2 * wave) * 512;
    _Float16* dC1 = lds + 12288 + (2 * wave + 1) * 512;

    int wm = wave & 1, wn = wave >> 1;
    // fragment read base: addr = base + i*512; per-lane = lane*8 halves (fully sequential banks)
    const _Float16* rAh = lds +          wm * 2048 + fq * 128 + fr * 8;
    const _Float16* rAl = rAh + 4096;
    const _Float16* rBh = lds + 8192 +   wn * 2048 + fq * 128 + fr * 8;
    const _Float16* rBl = rBh + 4096;

    floatx4 acc[4][4];
    #pragma unroll
    for (int i = 0; i < 4; ++i)
        #pragma unroll
        for (int j = 0; j < 4; ++j)
            acc[i][j] = (floatx4){0.f, 0.f, 0.f, 0.f};

    #pragma unroll
    for (int tap = 0; tap < 9; ++tap) {
        int dy = tap / 3 - 1, dx = tap % 3 - 1;
        const _Float16* gAh = ah + (size_t)(h + dy + 1) * ROWSTR + (dx + 1) * 8;
        const _Float16* gAl = al + (size_t)(h + dy + 1) * ROWSTR + (dx + 1) * 8;
        const _Float16* gBh = wh + (size_t)tap * TAPW;
        const _Float16* gBl = wl + (size_t)tap * TAPW;

        for (int kc = 0; kc < CIN; kc += 32) {
            int ab = (kc >> 5) * 4160;
            int bb = (kc >> 5) * 16384;
            glds16(gAh + ab + aoff0, dA0);
            glds16(gAh + ab + aoff1, dA1);
            glds16(gAl + ab + aoff0, dL0);
            glds16(gAl + ab + aoff1, dL1);
            glds16(gBh + bb + boff0, dB0);
            glds16(gBh + bb + boff1, dB1);
            glds16(gBl + bb + boff0, dC0);
            glds16(gBl + bb + boff1, dC1);
            __syncthreads();

            half8 fah[4], fal[4], fbh[4], fbl[4];
            #pragma unroll
            for (int i = 0; i < 4; ++i) {
                fah[i] = *(const half8*)(rAh + i * 512);
                fal[i] = *(const half8*)(rAl + i * 512);
                fbh[i] = *(const half8*)(rBh + i * 512);
                fbl[i] = *(const half8*)(rBl + i * 512);
            }
            #pragma unroll
            for (int i = 0; i < 4; ++i)
                #pragma unroll
                for (int j = 0; j < 4; ++j)
                    acc[i][j] = __builtin_amdgcn_mfma_f32_16x16x32_f16(fah[i], fbh[j], acc[i][j], 0, 0, 0);
            #pragma unroll
            for (int i = 0; i < 4; ++i)
                #pragma unroll
                for (int j = 0; j < 4; ++j)
                    acc[i][j] = __builtin_amdgcn_mfma_f32_16x16x32_f16(fah[i], fbl[j], acc[i][j], 0, 0, 0);
            #pragma unroll
            for (int i = 0; i < 4; ++i)
                #pragma unroll
                for (int j = 0; j < 4; ++j)
                    acc[i][j] = __builtin_amdgcn_mfma_f32_16x16x32_f16(fal[i], fbh[j], acc[i][j], 0, 0, 0);
            __syncthreads();
        }
    }

    const float scale = 1.f / 64.f;
    int em = 64 * wm + fq * 4;
    int en = 64 * wn + fr;
    #pragma unroll
    for (int j = 0; j < 4; ++j) {
        int oc = n0 + en + 16 * j;
        float b = bias[oc];
        #pragma unroll
        for (int i = 0; i < 4; ++i) {
            #pragma unroll
            for (int r = 0; r < 4; ++r) {
                int w = em + 16 * i + r;
                float v = fmaf(acc[i][j][r], scale, b);
                if (SPLIT_OUT) {
                    v = fmaxf(v, 0.f);
                    _Float16 hi = (_Float16)v;
                    size_t o = (size_t)(h + 1) * 66560 + (size_t)(oc >> 5) * 4160
                             + (size_t)((oc >> 3) & 3) * 1040 + (size_t)(w + 1) * 8 + (oc & 7);
                    oh[o] = hi;
                    ol[o] = (_Float16)(v - (float)hi);
                } else {
                    of[((size_t)h * HW + w) * COUTC + oc] = v;
                }
            }
        }
    }
}

// ---------------- fallback fp32 conv (old layouts) ----------------
template<int CIN, bool RELU_IN, bool RELU_OUT>
__global__ __launch_bounds__(256) void conv3x3_kernel(
    const float* __restrict__ in, const float* __restrict__ wgt,
    const float* __restrict__ bias, float* __restrict__ out)
{
    __shared__ float As[32][68];
    __shared__ float Bs[32][64];
    int bx = blockIdx.x;
    int mtile = bx & 255, ntile = bx >> 8;
    int h = mtile >> 1, w0 = (mtile & 1) << 6, n0 = ntile << 6;
    int tid = threadIdx.x, ty = tid >> 4, tx = tid & 15;
    float acc[4][4] = {{0.f}};
    const int KTOT = 9 * CIN;
    for (int k0 = 0; k0 < KTOT; k0 += 32) {
        int tap = k0 / CIN, icb = k0 % CIN;
        int dy = tap / 3 - 1, dx = tap % 3 - 1;
        int row = h + dy;
        bool rowok = ((unsigned)row < HW);
        {
            int pix = tid >> 3, cs = (tid & 7) << 2;
            #pragma unroll
            for (int p = 0; p < 2; ++p) {
                int px = pix + p * 32;
                int wcol = w0 + px + dx;
                float4 v = make_float4(0.f, 0.f, 0.f, 0.f);
                if (rowok && (unsigned)wcol < HW) {
                    v = *(const float4*)&in[((size_t)row * HW + wcol) * CIN + icb + cs];
                    if (RELU_IN) {
                        v.x = fmaxf(v.x, 0.f); v.y = fmaxf(v.y, 0.f);
                        v.z = fmaxf(v.z, 0.f); v.w = fmaxf(v.w, 0.f);
                    }
                }
                As[cs + 0][px] = v.x; As[cs + 1][px] = v.y;
                As[cs + 2][px] = v.z; As[cs + 3][px] = v.w;
            }
        }
        {
            int kr = tid >> 4, nc = (tid & 15) << 2;
            #pragma unroll
            for (int p = 0; p < 2; ++p) {
                int k = kr + p * 16;
                *(float4*)&Bs[k][nc] = *(const float4*)&wgt[(size_t)(k0 + k) * COUTC + n0 + nc];
            }
        }
        __syncthreads();
        #pragma unroll
        for (int kk = 0; kk < 32; ++kk) {
            float4 a = *(const float4*)&As[kk][ty << 2];
            float4 b = *(const float4*)&Bs[kk][tx << 2];
            float av[4] = {a.x, a.y, a.z, a.w};
            float bv[4] = {b.x, b.y, b.z, b.w};
            #pragma unroll
            for (int i = 0; i < 4; ++i)
                #pragma unroll
                for (int j = 0; j < 4; ++j)
                    acc[i][j] = fmaf(av[i], bv[j], acc[i][j]);
        }
        __syncthreads();
    }
    float4 bi = *(const float4*)&bias[n0 + (tx << 2)];
    float bv2[4] = {bi.x, bi.y, bi.z, bi.w};
    #pragma unroll
    for (int i = 0; i < 4; ++i) {
        float4 o;
        o.x = acc[i][0] + bv2[0]; o.y = acc[i][1] + bv2[1];
        o.z = acc[i][2] + bv2[2]; o.w = acc[i][3] + bv2[3];
        if (RELU_OUT) {
            o.x = fmaxf(o.x, 0.f); o.y = fmaxf(o.y, 0.f);
            o.z = fmaxf(o.z, 0.f); o.w = fmaxf(o.w, 0.f);
        }
        *(float4*)&out[((size_t)(h * HW) + w0 + (ty << 2) + i) * COUTC + n0 + (tx << 2)] = o;
    }
}

// ---------------- heads + sigmoid + decode + candidate filter ----------------
__global__ __launch_bounds__(256) void heads_decode_kernel(
    const float* __restrict__ x, const float* __restrict__ w_s, const float* __restrict__ b_s,
    const float* __restrict__ w_b, const float* __restrict__ b_b,
    float4* __restrict__ boxes, unsigned long long* __restrict__ keys,
    int* __restrict__ cnt, int* __restrict__ hist)
{
    __shared__ float xs[4][512];
    __shared__ float outs[4][45];
    int wave = threadIdx.x >> 6;
    int lane = threadIdx.x & 63;
    int pix  = blockIdx.x * 4 + wave;

    const float4* xp = (const float4*)&x[(size_t)pix * COUTC];
    *(float4*)&xs[wave][lane * 4]       = xp[lane];
    *(float4*)&xs[wave][256 + lane * 4] = xp[64 + lane];
    __syncthreads();

    if (lane < 45) {
        const float* wp; int stride; float acc;
        if (lane < 9) { wp = w_s + lane;       stride = 9;  acc = b_s[lane]; }
        else          { wp = w_b + (lane - 9); stride = 36; acc = b_b[lane - 9]; }
        const float* xrow = xs[wave];
        for (int k = 0; k < 512; k += 4) {
            acc = fmaf(xrow[k + 0], wp[(k + 0) * stride], acc);
            acc = fmaf(xrow[k + 1], wp[(k + 1) * stride], acc);
            acc = fmaf(xrow[k + 2], wp[(k + 2) * stride], acc);
            acc = fmaf(xrow[k + 3], wp[(k + 3) * stride], acc);
        }
        outs[wave][lane] = acc;
    }
    __syncthreads();

    if (lane < 9) {
        int h = pix >> 7, w = pix & 127;
        int a = lane;
        float z   = outs[wave][a];
        float dyv = outs[wave][9 + 4 * a + 0];
        float dxv = outs[wave][9 + 4 * a + 1];
        float dhv = outs[wave][9 + 4 * a + 2];
        float dwv = outs[wave][9 + 4 * a + 3];
        float sc  = (a < 3) ? 128.f : ((a < 6) ? 256.f : 512.f);
        int r = a - (a / 3) * 3;
        float ratio = (r == 0) ? 0.5f : ((r == 1) ? 1.f : 2.f);
        float sr = sqrtf(ratio);
        float ahh = sc * sr, aww = sc / sr;
        float acy = ((float)h + 0.5f) * 16.f;
        float acx = ((float)w + 0.5f) * 16.f;
        float cy = fmaf(dyv, ahh, acy);
        float cx = fmaf(dxv, aww, acx);
        float hh = ahh * expf(dhv);
        float ww = aww * expf(dwv);
        float y1 = fminf(fmaxf(cy - 0.5f * hh, 0.f), 2048.f);
        float x1 = fminf(fmaxf(cx - 0.5f * ww, 0.f), 2048.f);
        float y2 = fminf(fmaxf(cy + 0.5f * hh, 0.f), 2048.f);
        float x2 = fminf(fmaxf(cx + 0.5f * ww, 0.f), 2048.f);
        int gi = pix * 9 + a;
        boxes[gi] = make_float4(y1, x1, y2, x2);
        float s = 1.f / (1.f + expf(-z));
        if (s >= 0.5f) {
            unsigned u = __float_as_uint(s);
            unsigned d = 0x3F800000u - u;
            unsigned long long key = ((unsigned long long)d << 18) | (unsigned)gi;
            int p = atomicAdd(cnt, 1);
            keys[p] = key;
            atomicAdd(&hist[d >> 11], 1);
        }
    }
}

__global__ __launch_bounds__(256) void scan_kernel(
    const int* __restrict__ hist, int* __restrict__ base)
{
    __shared__ int buf[256];
    __shared__ int carry;
    int tid = threadIdx.x;
    if (tid == 0) carry = 0;
    __syncthreads();
    for (int c = 0; c < NB; c += 256) {
        int idx = c + tid;
        int v = (idx < NB) ? hist[idx] : 0;
        buf[tid] = v;
        __syncthreads();
        for (int s = 1; s < 256; s <<= 1) {
            int t = (tid >= s) ? buf[tid - s] : 0;
            __syncthreads();
            buf[tid] += t;
            __syncthreads();
        }
        if (idx < NB) base[idx] = carry + buf[tid] - v;
        __syncthreads();
        if (tid == 0) carry += buf[255];
        __syncthreads();
    }
    if (tid == 0) base[NB] = carry;
}

__global__ __launch_bounds__(256) void scatter_kernel(
    const unsigned long long* __restrict__ keys, const int* __restrict__ cnt,
    const int* __restrict__ base, int* __restrict__ cur,
    unsigned long long* __restrict__ skeys)
{
    int i = blockIdx.x * 256 + threadIdx.x;
    if (i < *cnt) {
        unsigned long long k = keys[i];
        int b = (int)(k >> 29);
        int p = base[b] + atomicAdd(&cur[b], 1);
        skeys[p] = k;
    }
}

// ---------------- sort within bucket (rank sort, one wave per bucket) ----------------
__global__ __launch_bounds__(64) void sortb_kernel(
    const unsigned long long* __restrict__ skeys, const int* __restrict__ base,
    unsigned long long* __restrict__ sk2)
{
    __shared__ unsigned long long sk[2048];
    int b = blockIdx.x;
    int s0 = base[b];
    int n = base[b + 1] - s0;
    if (n <= 0) return;
    int lane = threadIdx.x;
    if (n <= 2048) {
        for (int i = lane; i < n; i += 64) sk[i] = skeys[s0 + i];
        for (int i = lane; i < n; i += 64) {
            unsigned long long k = sk[i];
            int r = 0;
            for (int j = 0; j < n; ++j) r += (sk[j] < k) ? 1 : 0;
            sk2[s0 + r] = k;
        }
    } else {
        const unsigned long long* src = skeys + s0;
        for (int i = lane; i < n; i += 64) {
            unsigned long long k = src[i];
            int r = 0;
            for (int j = 0; j < n; ++j) r += (src[j] < k) ? 1 : 0;
            sk2[s0 + r] = k;
        }
    }
}

// ---------------- gather top-T boxes/areas ----------------
__global__ __launch_bounds__(256) void gather_kernel(
    const unsigned long long* __restrict__ sk2, const int* __restrict__ cnt,
    const float4* __restrict__ boxes, float4* __restrict__ cboxes, float* __restrict__ careas)
{
    int i = blockIdx.x * 256 + threadIdx.x;
    int Tc = min(*cnt, T_TOP);
    if (i < Tc) {
        unsigned long long k = sk2[i];
        float4 b = boxes[k & 0x3FFFFull];
        cboxes[i] = b;
        careas[i] = (b.z - b.x) * (b.w - b.y);
    }
}

// ---------------- pairwise suppression bitmask (upper triangle + diagonal self-bit) ----------------
__global__ __launch_bounds__(256) void mask_kernel(
    const float4* __restrict__ cboxes, const float* __restrict__ careas,
    unsigned long long* __restrict__ msk)
{
    int bi = blockIdx.y, bj = blockIdx.x;
    if (bj < bi) return;                 // lower-triangle words stay garbage (harmless: consumed j's)
    __shared__ float4 jb[256];
    __shared__ float  ja[256];
    int t = threadIdx.x;
    int j0 = bj << 8;
    jb[t] = cboxes[j0 + t];
    ja[t] = careas[j0 + t];
    __syncthreads();
    int i = (bi << 8) + t;
    float4 ci = cboxes[i];
    float ca = careas[i];
    unsigned long long word = 0;
    for (int jj = 0; jj < 256; ++jj) {
        int j = j0 + jj;
        float4 b = jb[jj];
        float iy = fmaxf(0.f, fminf(ci.z, b.z) - fmaxf(ci.x, b.x));
        float ix = fmaxf(0.f, fminf(ci.w, b.w) - fmaxf(ci.y, b.y));
        float inter = iy * ix;
        float iou = inter / (ca + ja[jj] - inter + 1e-9f);
        bool bit = (j == i) || (j > i && iou > 0.7f);
        if (bit) word |= 1ull << (jj & 63);
        if ((jj & 63) == 63) {
            msk[(size_t)i * TW + (bj << 2) + (jj >> 6)] = word;
            word = 0;
        }
    }
}

// ---------------- greedy NMS walk over bitmask (single wave) + exact tail ----------------
__global__ __launch_bounds__(64) void walk_kernel(
    const unsigned long long* __restrict__ sk2, const int* __restrict__ cnt,
    const float4* __restrict__ cboxes, const float* __restrict__ careas,
    const unsigned long long* __restrict__ msk, const float4* __restrict__ boxes,
    float* __restrict__ out)
{
    __shared__ unsigned long long sup[TW];
    __shared__ float4 sbox[NSEL];
    __shared__ float  sarea[NSEL];
    int lane = threadIdx.x;
    for (int i = lane; i < 1800; i += 64) out[i] = 0.f;
    #pragma unroll
    for (int k = 0; k < 4; ++k) sup[lane * 4 + k] = 0ull;

    int total = *cnt;
    int Tc = min(total, T_TOP);
    int sel = 0;
    bool done = false;
    for (int w = 0; w < TW && !done; ++w) {
        unsigned long long cur = sup[w];
        while (cur != ~0ull) {
            int j = __builtin_ctzll(~cur);
            int idx = (w << 6) + j;
            if (idx >= Tc) { done = true; break; }
            float4 cb = cboxes[idx];
            float ca = careas[idx];
            if (lane == 0) {
                unsigned long long key = sk2[idx];
                out[sel * 4 + 0] = cb.x; out[sel * 4 + 1] = cb.y;
                out[sel * 4 + 2] = cb.z; out[sel * 4 + 3] = cb.w;
                out[1200 + sel] = __uint_as_float(0x3F800000u - (unsigned)(key >> 18));
                out[1500 + sel] = 1.f;
                sbox[sel] = cb;
                sarea[sel] = ca;
            }
            sel++;
            if (sel >= NSEL) { done = true; break; }
            const unsigned long long* row = msk + (size_t)idx * TW;
            #pragma unroll
            for (int k = 0; k < 4; ++k)
                sup[lane * 4 + k] |= row[lane * 4 + k];
            cur = sup[w];
        }
    }
    // exact tail beyond T_TOP (expected never at current sizes)
    if (sel < NSEL && total > T_TOP) {
        for (int i = T_TOP; i < total && sel < NSEL; ++i) {
            unsigned long long key = sk2[i];
            float4 cb = boxes[key & 0x3FFFFull];
            float ca = (cb.z - cb.x) * (cb.w - cb.y);
            int supp = 0;
            for (int t = lane; t < sel; t += 64) {
                float4 s4 = sbox[t];
                float iy = fmaxf(0.f, fminf(s4.z, cb.z) - fmaxf(s4.x, cb.x));
                float ix = fmaxf(0.f, fminf(s4.w, cb.w) - fmaxf(s4.y, cb.y));
                float inter = iy * ix;
                float iou = inter / (sarea[t] + ca - inter + 1e-9f);
                if (iou > 0.7f) supp = 1;
            }
            if (__ballot(supp) == 0ull) {
                if (lane == 0) {
                    out[sel * 4 + 0] = cb.x; out[sel * 4 + 1] = cb.y;
                    out[sel * 4 + 2] = cb.z; out[sel * 4 + 3] = cb.w;
                    out[1200 + sel] = __uint_as_float(0x3F800000u - (unsigned)(key >> 18));
                    out[1500 + sel] = 1.f;
                    sbox[sel] = cb;
                    sarea[sel] = ca;
                }
                sel++;
            }
        }
    }
}

extern "C" void kernel_launch(void* const* d_in, const int* in_sizes, int n_in,
                              void* d_out, int out_size, void* d_ws, size_t ws_size,
                              hipStream_t stream) {
    const float* feat = (const float*)d_in[0];
    const float* w1   = (const float*)d_in[1];
    const float* b1   = (const float*)d_in[2];
    const float* w2   = (const float*)d_in[3];
    const float* b2   = (const float*)d_in[4];
    const float* w_s  = (const float*)d_in[5];
    const float* b_s  = (const float*)d_in[6];
    const float* w_b  = (const float*)d_in[7];
    const float* b_b  = (const float*)d_in[8];
    float* out = (float*)d_out;
    char* ws = (char*)d_ws;

    if (ws_size >= NWS_TOTAL) {
        _Float16* a1h = (_Float16*)(ws + NWS_A1H);
        _Float16* a1l = (_Float16*)(ws + NWS_A1L);
        _Float16* w1h = (_Float16*)(ws + NWS_W1H);
        _Float16* w1l = (_Float16*)(ws + NWS_W1L);
        _Float16* a2h = (_Float16*)(ws + NWS_A2H);
        _Float16* a2l = (_Float16*)(ws + NWS_A2L);
        _Float16* w2h = (_Float16*)(ws + NWS_W2H);
        _Float16* w2l = (_Float16*)(ws + NWS_W2L);
        float* x2 = (float*)(ws + NWS_X2);
        float4* boxes = (float4*)(ws + NWS_BOXES);
        unsigned long long* keys  = (unsigned long long*)(ws + NWS_KEYS);
        unsigned long long* skeys = (unsigned long long*)(ws + NWS_SKEYS);
        int* hist = (int*)(ws + NWS_HIST);
        int* cur  = (int*)(ws + NWS_CUR);
        int* cnt  = (int*)(ws + NWS_CNT);
        int* base = (int*)(ws + NWS_BASE);
        // NMS-time reuse of conv1-input regions:
        unsigned long long* msk = (unsigned long long*)(ws + NWS_A1H);       // 32 MB
        float4* cbox  = (float4*)(ws + NWS_A1L);                             // 256 KB
        float*  carea = (float*)(ws + NWS_A1L + 262144);                     // 64 KB
        unsigned long long* sk2 = keys;                                      // keys dead after scatter

        hipMemsetAsync(ws + NWS_HIST, 0, (NWS_CNT - NWS_HIST) + 256, stream);
        convert_feat_kernel<<<16900, 256, 0, stream>>>(feat, a1h, a1l);
        convert_w_kernel<1024><<<2304, 256, 0, stream>>>(w1, w1h, w1l);
        convert_w_kernel< 512><<<1152, 256, 0, stream>>>(w2, w2h, w2l);
        zero_pads_kernel<<<516, 256, 0, stream>>>(a2h, a2l);
        conv_mfma_kernel<1024, true ><<<512, 256, 0, stream>>>(a1h, a1l, w1h, w1l, b1, a2h, a2l, nullptr);
        conv_mfma_kernel< 512, false><<<512, 256, 0, stream>>>(a2h, a2l, w2h, w2l, b2, nullptr, nullptr, x2);
        heads_decode_kernel<<<4096, 256, 0, stream>>>(x2, w_s, b_s, w_b, b_b, boxes, keys, cnt, hist);
        scan_kernel<<<1, 256, 0, stream>>>(hist, base);
        scatter_kernel<<<576, 256, 0, stream>>>(keys, cnt, base, cur, skeys);
        sortb_kernel<<<NB, 64, 0, stream>>>(skeys, base, sk2);
        gather_kernel<<<64, 256, 0, stream>>>(sk2, cnt, boxes, cbox, carea);
        mask_kernel<<<dim3(64, 64), 256, 0, stream>>>(cbox, carea, msk);
        walk_kernel<<<1, 64, 0, stream>>>(sk2, cnt, cbox, carea, msk, boxes, out);
    } else {
        float* x1 = (float*)(ws + WS_X1);
        float* x2 = (float*)(ws + WS_X2);
        float4* boxes = (float4*)(ws + WS_BOXES);
        unsigned long long* keys  = (unsigned long long*)(ws + WS_KEYS);
        unsigned long long* skeys = (unsigned long long*)(ws + WS_SKEYS);
        int* hist = (int*)(ws + WS_HIST);
        int* cur  = (int*)(ws + WS_CUR);
        int* cnt  = (int*)(ws + WS_CNT);
        int* base = (int*)(ws + WS_BASE);
        unsigned long long* msk = (unsigned long long*)(ws + WS_X1);   // x1 dead after conv2 (32 MB exact)
        float4* cbox  = (float4*)(ws + WS_X2);                         // x2 dead after heads
        float*  carea = (float*)(ws + WS_X2 + 262144);
        unsigned long long* sk2 = keys;

        hipMemsetAsync(ws + WS_HIST, 0, (WS_CNT - WS_HIST) + 256, stream);
        conv3x3_kernel<1024, true,  true ><<<2048, 256, 0, stream>>>(feat, w1, b1, x1);
        conv3x3_kernel< 512, false, false><<<2048, 256, 0, stream>>>(x1,   w2, b2, x2);
        heads_decode_kernel<<<4096, 256, 0, stream>>>(x2, w_s, b_s, w_b, b_b, boxes, keys, cnt, hist);
        scan_kernel<<<1, 256, 0, stream>>>(hist, base);
        scatter_kernel<<<576, 256, 0, stream>>>(keys, cnt, base, cur, skeys);
        sortb_kernel<<<NB, 64, 0, stream>>>(skeys, base, sk2);
        gather_kernel<<<64, 256, 0, stream>>>(sk2, cnt, boxes, cbox, carea);
        mask_kernel<<<dim3(64, 64), 256, 0, stream>>>(cbox, carea, msk);
        walk_kernel<<<1, 64, 0, stream>>>(sk2, cnt, cbox, carea, msk, boxes, out);
    }
}